// Round 3
// baseline (1803.487 us; speedup 1.0000x reference)
//
#include <hip/hip_runtime.h>
#include <math.h>

// Problem constants
#define T_STEPS 256
#define BB 8
#define NSTATE 64
#define DD 80
#define PP 256
#define HH 512
#define OO 512
#define NPARAM 161   // 2*D+1
#define PLS 171      // padded row stride for params in LDS (bank spread)
#define NEG_INF_F (-1000000.0f)

// lstm config
#define LB 128       // lstm blocks (4 j-units each)
#define LT 256       // lstm threads per block
#define HSTR 516     // hl row stride (floats) — bank spread
#define WSTR 516     // wl row stride
#define RSTR 132     // red row stride

typedef __attribute__((ext_vector_type(8))) short s16x8;
typedef __attribute__((ext_vector_type(4))) float f32x4;

union PairU { double d; float f[2]; unsigned u[2]; };

__device__ __forceinline__ float sigmoidf_(float x) { return 1.0f / (1.0f + __expf(-x)); }
__device__ __forceinline__ short bf16rne(float x) {
  union { float f; unsigned u; } v; v.f = x;
  unsigned r = (v.u + 0x7FFFu + ((v.u >> 16) & 1u)) >> 16;
  return (short)r;
}

// ---------------------------------------------------------------------------
// prep kernels
// ---------------------------------------------------------------------------
__global__ void ar_fill(const float* __restrict__ mels, float* __restrict__ ar) {
  int idx = blockIdx.x * 256 + threadIdx.x;
  if (idx >= T_STEPS * BB * DD) return;
  int d = idx % DD; int r = idx / DD; int b = r % BB; int t = r / BB;
  ar[idx] = (t == 0) ? 0.0f : mels[(b * DD + d) * T_STEPS + (t - 1)];
}

// w2frag[((kb*12+nt)*64+lane)*8+j] = bf16(out_w2[p][o]), p=nt*16+(lane&15),
// o=kb*32+8*(lane>>4)+j  (B-fragment layout for mfma_f32_16x16x32_bf16)
__global__ void w2frag_fill(const float* __restrict__ w2, short* __restrict__ wf) {
  int idx = blockIdx.x * 256 + threadIdx.x;
  if (idx >= 16 * 12 * 64 * 8) return;
  int j = idx & 7, lane = (idx >> 3) & 63, nt = (idx >> 9) % 12, kb = idx / 6144;
  int p = nt * 16 + (lane & 15);
  int o = kb * 32 + ((lane >> 4) << 3) + j;
  float v = (p < NPARAM) ? w2[p * OO + o] : 0.0f;
  wf[idx] = bf16rne(v);
}

__global__ void clear_hm(float* __restrict__ p) {
  int i = blockIdx.x * 256 + threadIdx.x;
  if (i < 32768) p[i] = 0.0f;
}

// ---------------------------------------------------------------------------
// generic tiled fp32 GEMM:  C[m][n] = act( sum_k A[m][aoff+k]*B[n][boff+k] + bias )
// ---------------------------------------------------------------------------
__global__ __launch_bounds__(256)
void gemm_nt(const float* __restrict__ A, int lda, int aoff,
             const float* __restrict__ Bw, int ldb, int boff,
             const float* __restrict__ bias1, const float* __restrict__ bias2,
             float* __restrict__ C, int M, int N, int K, int relu)
{
  __shared__ float As[32][64];
  __shared__ float Bs[32][64];
  const int tid = threadIdx.x;
  const int m0 = blockIdx.y * 64, n0 = blockIdx.x * 64;
  const int tm = tid & 15, tn = tid >> 4;
  float acc[4][4] = {{0.f,0.f,0.f,0.f},{0.f,0.f,0.f,0.f},{0.f,0.f,0.f,0.f},{0.f,0.f,0.f,0.f}};

  for (int k0 = 0; k0 < K; k0 += 32) {
#pragma unroll
    for (int half = 0; half < 2; ++half) {
      int mm = (tid >> 3) + half * 32;
      int kk = (tid & 7) * 4;
      const float* ap = &A[(size_t)(m0 + mm) * lda + aoff + k0 + kk];
      float4 av;
      if (k0 + kk + 3 < K) {
        av = *(const float4*)ap;
      } else {
        av.x = (k0 + kk + 0 < K) ? ap[0] : 0.f;
        av.y = (k0 + kk + 1 < K) ? ap[1] : 0.f;
        av.z = (k0 + kk + 2 < K) ? ap[2] : 0.f;
        av.w = (k0 + kk + 3 < K) ? ap[3] : 0.f;
      }
      As[kk + 0][mm] = av.x; As[kk + 1][mm] = av.y;
      As[kk + 2][mm] = av.z; As[kk + 3][mm] = av.w;
      const float* bp = &Bw[(size_t)(n0 + mm) * ldb + boff + k0 + kk];
      float4 bv;
      if (k0 + kk + 3 < K) {
        bv = *(const float4*)bp;
      } else {
        bv.x = (k0 + kk + 0 < K) ? bp[0] : 0.f;
        bv.y = (k0 + kk + 1 < K) ? bp[1] : 0.f;
        bv.z = (k0 + kk + 2 < K) ? bp[2] : 0.f;
        bv.w = (k0 + kk + 3 < K) ? bp[3] : 0.f;
      }
      Bs[kk + 0][mm] = bv.x; Bs[kk + 1][mm] = bv.y;
      Bs[kk + 2][mm] = bv.z; Bs[kk + 3][mm] = bv.w;
    }
    __syncthreads();
#pragma unroll
    for (int kk = 0; kk < 32; ++kk) {
      float4 a4 = *(const float4*)&As[kk][tm * 4];
      float4 b4 = *(const float4*)&Bs[kk][tn * 4];
      float av[4] = {a4.x, a4.y, a4.z, a4.w};
      float bvv[4] = {b4.x, b4.y, b4.z, b4.w};
#pragma unroll
      for (int i = 0; i < 4; ++i)
#pragma unroll
        for (int j = 0; j < 4; ++j)
          acc[i][j] += av[i] * bvv[j];
    }
    __syncthreads();
  }

  float bj[4];
#pragma unroll
  for (int j = 0; j < 4; ++j) {
    int n = n0 + tn * 4 + j;
    float bv = 0.f;
    if (bias1) bv += bias1[n];
    if (bias2) bv += bias2[n];
    bj[j] = bv;
  }
#pragma unroll
  for (int i = 0; i < 4; ++i) {
    int m = m0 + tm * 4 + i;
    float4 v;
    v.x = acc[i][0] + bj[0]; v.y = acc[i][1] + bj[1];
    v.z = acc[i][2] + bj[2]; v.w = acc[i][3] + bj[3];
    if (relu) {
      v.x = fmaxf(v.x, 0.f); v.y = fmaxf(v.y, 0.f);
      v.z = fmaxf(v.z, 0.f); v.w = fmaxf(v.w, 0.f);
    }
    *(float4*)&C[(size_t)m * N + n0 + tn * 4] = v;
  }
}

// ---------------------------------------------------------------------------
// persistent sequential LSTM v3: tagged mailbox {h, tag=t+1} in 8B atomics,
// 4-deep ring (overwrite provably impossible at distance 4; ring cleared per
// launch so stale tags from a previous graph replay can't collide).
// Data arrival IS the sync: no flags, no grid barrier, no vmcnt-drain hop.
// ---------------------------------------------------------------------------
__global__ __launch_bounds__(LT)
void lstm_seq(const float* __restrict__ w_hh, const float* __restrict__ gates_x,
              float* __restrict__ h_all, double* __restrict__ hm)
{
  __shared__ float wl[16][WSTR];
  __shared__ float hl[8][HSTR];
  __shared__ float red[16][RSTR];
  __shared__ float gl[128];
  const int tid = threadIdx.x;
  const int blk = blockIdx.x;
  const int j0 = blk * 4;

  for (int r = 0; r < 16; ++r) {
    int g = r >> 2, jl = r & 3;
    const float* src = &w_hh[((size_t)(g * HH + j0 + jl)) * HH];
    for (int k = tid; k < HH; k += LT) wl[r][k] = src[k];
  }

  const int rg  = tid >> 6;
  const int bg  = (tid >> 4) & 3;
  const int ksl = tid & 15;
  const int cjl = tid >> 3, cb = tid & 7;   // tid<32 mapping
  float c_reg = 0.f;

  for (int t = 0; t < T_STEPS; ++t) {
    // prefetch gates_x early (independent of h[t-1])
    float gx = 0.f;
    if (tid < 128) {
      int r = tid >> 3, b = tid & 7, g = r >> 2, jl = r & 3;
      gx = gates_x[((size_t)t * BB + b) * (4 * HH) + g * HH + j0 + jl];
    }
    __builtin_amdgcn_sched_barrier(0);

    // ---- acquire h[t-1] via tagged mailbox ----
    if (t == 0) {
      for (int i = tid; i < 8 * HSTR; i += LT) ((float*)hl)[i] = 0.f;
    } else {
      const double* ring = hm + (size_t)((t - 1) & 3) * 4096;
      unsigned pend = 0xFFFFu;
      do {
        double v[16];
#pragma unroll
        for (int q = 0; q < 16; ++q)
          v[q] = __hip_atomic_load(&ring[q * 256 + tid], __ATOMIC_RELAXED, __HIP_MEMORY_SCOPE_AGENT);
#pragma unroll
        for (int q = 0; q < 16; ++q) {
          PairU w; w.d = v[q];
          if (((pend >> q) & 1u) && w.u[1] == (unsigned)t) {
            int s = q * 256 + tid;
            hl[s >> 9][s & 511] = w.f[0];
            pend &= ~(1u << q);
          }
        }
        if (pend) __builtin_amdgcn_s_sleep(2);
      } while (pend);
    }
    __syncthreads();

    // ---- partial matvec ----
    float acc[4][2] = {{0.f,0.f},{0.f,0.f},{0.f,0.f},{0.f,0.f}};
#pragma unroll
    for (int i = 0; i < 8; ++i) {
      const int k = ksl * 4 + 64 * i;
      float4 h0 = *(const float4*)&hl[bg * 2][k];
      float4 h1 = *(const float4*)&hl[bg * 2 + 1][k];
#pragma unroll
      for (int rl = 0; rl < 4; ++rl) {
        float4 w = *(const float4*)&wl[rg * 4 + rl][k];
        acc[rl][0] += w.x * h0.x + w.y * h0.y + w.z * h0.z + w.w * h0.w;
        acc[rl][1] += w.x * h1.x + w.y * h1.y + w.z * h1.z + w.w * h1.w;
      }
    }
#pragma unroll
    for (int rl = 0; rl < 4; ++rl)
#pragma unroll
      for (int bl = 0; bl < 2; ++bl)
        red[ksl][(rg * 4 + rl) * 8 + bg * 2 + bl] = acc[rl][bl];
    __syncthreads();

    // ---- k-reduction + bias ----
    if (tid < 128) {
      float s = gx;
#pragma unroll
      for (int p = 0; p < 16; ++p) s += red[p][tid];
      gl[tid] = s;
    }
    __syncthreads();

    // ---- c/h update + publish (tagged pair is both data and signal) ----
    if (tid < 32) {
      float iv = gl[(0 * 4 + cjl) * 8 + cb];
      float fv = gl[(1 * 4 + cjl) * 8 + cb];
      float gv = gl[(2 * 4 + cjl) * 8 + cb];
      float ov = gl[(3 * 4 + cjl) * 8 + cb];
      float ct = sigmoidf_(fv) * c_reg + sigmoidf_(iv) * tanhf(gv);
      c_reg = ct;
      float h = sigmoidf_(ov) * tanhf(ct);
      PairU pv; pv.f[0] = h; pv.u[1] = (unsigned)(t + 1);
      __hip_atomic_store(&hm[(size_t)(t & 3) * 4096 + cb * 512 + j0 + cjl], pv.d,
                         __ATOMIC_RELAXED, __HIP_MEMORY_SCOPE_AGENT);
      h_all[((size_t)t * BB + cb) * HH + j0 + cjl] = h;  // plain copy for hv-gemm
    }
    // no trailing barrier: hl rewrite next iter is ordered by the two barriers above
  }
}

// ---------------------------------------------------------------------------
// fused output net + emission, MFMA version. Block per (t,b), 4 waves.
// A = hid (64 states x 512) bf16, generated in-fragment-layout into LDS
// (double-buffered 4KB per kb); B = w2frag bf16 from global (L2-resident).
// C tiles: wave w owns cols p in [w*48, w*48+48), all 64 state-rows.
// D lane map (verified m89): row=(lane>>4)*4+reg, col=lane&15.
// ---------------------------------------------------------------------------
__global__ __launch_bounds__(256)
void outnet(const float* __restrict__ hv, const float* __restrict__ zi,
            const short* __restrict__ w2frag, const float* __restrict__ b2,
            const float* __restrict__ mels, const int* __restrict__ inputs_len,
            float* __restrict__ em_out, float* __restrict__ lsn_out,
            float* __restrict__ lsp_out)
{
  __shared__ float hvs[OO];
  __shared__ float xts[96];
  __shared__ s16x8 Afr[2][256];     // [buf][(mt*64+lane)] of 8 bf16
  __shared__ float pl[64 * PLS];
  const int tid = threadIdx.x;
  const int tb = blockIdx.x;
  const int t = tb >> 3, b = tb & 7;
  const int lane = tid & 63, wv = tid >> 6;

  if (tid < 128) *(float4*)&hvs[tid * 4] = *(const float4*)&hv[(size_t)tb * OO + tid * 4];
  if (tid < DD) xts[tid] = mels[(b * DD + tid) * T_STEPS + t];
  __syncthreads();

  // A-gen: this thread produces the fragment slot (mt=wv, lane) each kb:
  // A[row = mt*16+(lane&15)][k = kb*32 + 8*(lane>>4) + j]
  const int n_state = wv * 16 + (lane & 15);
  const int osub = (lane >> 4) * 8;
  const float* zbase = zi + (size_t)(b * 64 + n_state) * OO;

  auto genA = [&](int kb, int buf) {
    int ob = kb * 32 + osub;
    float4 z0 = *(const float4*)&zbase[ob];
    float4 z1 = *(const float4*)&zbase[ob + 4];
    float4 h0 = *(const float4*)&hvs[ob];
    float4 h1 = *(const float4*)&hvs[ob + 4];
    s16x8 s;
    s[0] = bf16rne(fmaxf(z0.x + h0.x, 0.f));
    s[1] = bf16rne(fmaxf(z0.y + h0.y, 0.f));
    s[2] = bf16rne(fmaxf(z0.z + h0.z, 0.f));
    s[3] = bf16rne(fmaxf(z0.w + h0.w, 0.f));
    s[4] = bf16rne(fmaxf(z1.x + h1.x, 0.f));
    s[5] = bf16rne(fmaxf(z1.y + h1.y, 0.f));
    s[6] = bf16rne(fmaxf(z1.z + h1.z, 0.f));
    s[7] = bf16rne(fmaxf(z1.w + h1.w, 0.f));
    Afr[buf][tid] = s;
  };
  genA(0, 0);

  f32x4 acc[4][3];
#pragma unroll
  for (int m = 0; m < 4; ++m)
#pragma unroll
    for (int n = 0; n < 3; ++n) acc[m][n] = (f32x4){0.f, 0.f, 0.f, 0.f};

  // b-frag base for this wave: nt = wv*3 + ntl
  const short* bfp = w2frag + ((size_t)(wv * 3) * 64 + lane) * 8;

  for (int kb = 0; kb < 16; ++kb) {
    __syncthreads();
    s16x8 bf[3];
#pragma unroll
    for (int ntl = 0; ntl < 3; ++ntl)
      bf[ntl] = *(const s16x8*)&bfp[(size_t)kb * 6144 + ntl * 512];
    if (kb < 15) genA(kb + 1, (kb + 1) & 1);
    s16x8 af[4];
#pragma unroll
    for (int m = 0; m < 4; ++m) af[m] = Afr[kb & 1][m * 64 + lane];
#pragma unroll
    for (int m = 0; m < 4; ++m)
#pragma unroll
      for (int ntl = 0; ntl < 3; ++ntl)
        acc[m][ntl] = __builtin_amdgcn_mfma_f32_16x16x32_bf16(af[m], bf[ntl], acc[m][ntl], 0, 0, 0);
  }

  // params -> pl
  const int prow4 = (lane >> 4) * 4;
#pragma unroll
  for (int ntl = 0; ntl < 3; ++ntl) {
    int p = (wv * 3 + ntl) * 16 + (lane & 15);
    if (p < NPARAM) {
      float bb2 = b2[p];
#pragma unroll
      for (int m = 0; m < 4; ++m)
#pragma unroll
        for (int r = 0; r < 4; ++r)
          pl[(m * 16 + prow4 + r) * PLS + p] = acc[m][ntl][r] + bb2;
    }
  }
  __syncthreads();

  // emission + transition log-sigmoids
  const int ne = tid >> 2, dq = tid & 3;
  float s = 0.f;
  for (int d = dq * 20; d < dq * 20 + 20; ++d) {
    float mean = pl[ne * PLS + d];
    float sp   = pl[ne * PLS + 80 + d];
    float x = xts[d];
    float sf = (sp > 20.f) ? sp : log1pf(__expf(sp));
    float sd = fmaxf(sf, 0.001f);
    float zz = (x - mean) / sd;
    s += -0.5f * zz * zz - __logf(sd) - 0.91893853320467274f;
  }
  s += __shfl_xor(s, 1);
  s += __shfl_xor(s, 2);
  if (dq == 0) {
    int ilen = inputs_len[b];
    em_out[(size_t)tb * NSTATE + ne] = (ne < ilen) ? s : 0.f;
    float tv = pl[ne * PLS + 160];
    lsp_out[(size_t)tb * NSTATE + ne] = __logf(fmaxf(sigmoidf_(tv), 1e-4f));
    lsn_out[(size_t)tb * NSTATE + ne] = __logf(fmaxf(sigmoidf_(-tv), 1e-4f));
  }
}

// ---------------------------------------------------------------------------
// sequential HMM forward scan: 1 block, wave per batch, alpha in registers.
// ---------------------------------------------------------------------------
__global__ __launch_bounds__(512)
void hmm_scan(const float* __restrict__ em, const float* __restrict__ lsn,
              const float* __restrict__ lsp, const int* __restrict__ inputs_len,
              const int* __restrict__ mel_lens, float* __restrict__ out)
{
  const int tid = threadIdx.x;
  const int b = tid >> 6, n = tid & 63;
  const int ilen = inputs_len[b], mlen = mel_lens[b];
  const bool mask = n < ilen;
  float alpha = 0.f, slc = 0.f, la = NEG_INF_F, llsp = 0.f;

  for (int t = 0; t < T_STEPS; ++t) {
    size_t base = ((size_t)t * BB + b) * NSTATE + n;
    float e = em[base], ln_ = lsn[base], lp_ = lsp[base];
    float at;
    if (t == 0) {
      at = ((n == 0) ? 0.f : NEG_INF_F) + e;
    } else {
      float stay = alpha + ln_;
      float lvs = alpha + lp_;
      float lv = __shfl_up(lvs, 1, 64);
      if (n == 0) lv = NEG_INF_F;
      float mx = fmaxf(stay, lv), mn = fminf(stay, lv);
      float tt = mask ? (mx + log1pf(__expf(mn - mx))) : NEG_INF_F;
      at = e + tt;
    }
    float m = at;
#pragma unroll
    for (int off = 1; off < 64; off <<= 1) m = fmaxf(m, __shfl_xor(m, off));
    float es = __expf(at - m);
#pragma unroll
    for (int off = 1; off < 64; off <<= 1) es += __shfl_xor(es, off);
    float logc = m + __logf(es);
    alpha = at - logc;
    if (t < mlen) slc += logc;
    if (t == mlen - 1) { la = mask ? alpha : NEG_INF_F; llsp = lp_; }
  }

  float v = la + ((n == ilen - 1) ? llsp : NEG_INF_F);
  float m = v;
#pragma unroll
  for (int off = 1; off < 64; off <<= 1) m = fmaxf(m, __shfl_xor(m, off));
  float es = __expf(v - m);
#pragma unroll
  for (int off = 1; off < 64; off <<= 1) es += __shfl_xor(es, off);
  float sfin = m + __logf(es);
  if (n == 0) out[b] = slc + sfin;
}

// ---------------------------------------------------------------------------
extern "C" void kernel_launch(void* const* d_in, const int* in_sizes, int n_in,
                              void* d_out, int out_size, void* d_ws, size_t ws_size,
                              hipStream_t stream)
{
  const float* inputs    = (const float*)d_in[0];
  const float* mels      = (const float*)d_in[1];
  const float* prenet_w1 = (const float*)d_in[2];
  const float* prenet_w2 = (const float*)d_in[3];
  const float* w_ih      = (const float*)d_in[4];
  const float* w_hh      = (const float*)d_in[5];
  const float* b_ih      = (const float*)d_in[6];
  const float* b_hh      = (const float*)d_in[7];
  const float* out_w1    = (const float*)d_in[8];
  const float* out_b1    = (const float*)d_in[9];
  const float* out_w2    = (const float*)d_in[10];
  const float* out_b2    = (const float*)d_in[11];
  const int* inputs_len  = (const int*)d_in[12];
  const int* mel_lens    = (const int*)d_in[13];

  float* ws = (float*)d_ws;
  float* ar      = ws;                       // 163840
  float* p1      = ar + 163840;              // 524288
  float* p2      = p1 + 524288;              // 524288
  float* gates_x = p2 + 524288;              // 4194304
  float* ziT     = gates_x + 4194304;        // 262144  (plain [b*64+n][o])
  short* w2frag  = (short*)(ziT + 262144);   // 98304 shorts (in 98304-float slot)
  float* h_all   = ziT + 262144 + 98304;     // 1048576
  float* hv      = h_all + 1048576;          // 1048576
  float* em      = hv + 1048576;             // 131072
  float* lsn     = em + 131072;              // 131072
  float* lsp     = lsn + 131072;             // 131072
  double* hm     = (double*)(lsp + 131072);  // 16384 doubles (32768 floats)

  // time-parallel precompute
  ar_fill<<<640, 256, 0, stream>>>(mels, ar);
  w2frag_fill<<<384, 256, 0, stream>>>(out_w2, w2frag);
  clear_hm<<<128, 256, 0, stream>>>((float*)hm);

  // p1 = relu(ar @ w1^T)                 M=2048 N=256 K=80
  gemm_nt<<<dim3(4, 32), 256, 0, stream>>>(ar, DD, 0, prenet_w1, DD, 0,
                                           nullptr, nullptr, p1, 2048, PP, DD, 1);
  // p2 = relu(p1 @ w2^T)                 M=2048 N=256 K=256
  gemm_nt<<<dim3(4, 32), 256, 0, stream>>>(p1, PP, 0, prenet_w2, PP, 0,
                                           nullptr, nullptr, p2, 2048, PP, PP, 1);
  // gates_x = p2 @ w_ih^T + b_ih + b_hh  M=2048 N=2048 K=256
  gemm_nt<<<dim3(32, 32), 256, 0, stream>>>(p2, PP, 0, w_ih, PP, 0,
                                            b_ih, b_hh, gates_x, 2048, 2048, PP, 0);
  // ziT[(b*64+n)][o] = inputs @ W1_e^T + b1   M=512 N=512 K=512
  gemm_nt<<<dim3(8, 8), 256, 0, stream>>>(inputs, 512, 0, out_w1, 1024, 512,
                                          out_b1, nullptr, ziT, 512, OO, 512, 0);

  // sequential LSTM (tagged mailbox)
  lstm_seq<<<LB, LT, 0, stream>>>(w_hh, gates_x, h_all, hm);

  // hv = h_all @ W1_h^T                  M=2048 N=512 K=512
  gemm_nt<<<dim3(8, 32), 256, 0, stream>>>(h_all, HH, 0, out_w1, 1024, 0,
                                           nullptr, nullptr, hv, 2048, OO, HH, 0);

  // fused output net + emission (MFMA)
  outnet<<<2048, 256, 0, stream>>>(hv, ziT, w2frag, out_b2, mels, inputs_len,
                                   em, lsn, lsp);

  // sequential HMM scan
  hmm_scan<<<1, 512, 0, stream>>>(em, lsn, lsp, inputs_len, mel_lens, (float*)d_out);
}

// Round 4
// 1761.507 us; speedup vs baseline: 1.0238x; 1.0238x over previous
//
#include <hip/hip_runtime.h>
#include <math.h>

// Problem constants
#define T_STEPS 256
#define BB 8
#define NSTATE 64
#define DD 80
#define PP 256
#define HH 512
#define OO 512
#define NPARAM 161   // 2*D+1
#define PLS 171      // padded row stride for params in LDS (bank spread)
#define NEG_INF_F (-1000000.0f)

// lstm config
#define LB 128       // lstm blocks (4 j-units each)
#define LT 256       // lstm threads per block
#define HSTR 516     // hl row stride (floats) — bank spread
#define WSTR 516     // wl row stride

#define GSTR 88      // gemm_mfma LDS row stride in ushorts (176B: 16B-aligned, 2-way banks)

typedef __attribute__((ext_vector_type(8))) short s16x8;
typedef __attribute__((ext_vector_type(4))) float f32x4;

union PairU { double d; float f[2]; unsigned u[2]; };

__device__ __forceinline__ float sigmoidf_(float x) { return 1.0f / (1.0f + __expf(-x)); }
__device__ __forceinline__ unsigned short bf16rne(float x) {
  union { float f; unsigned u; } v; v.f = x;
  unsigned r = (v.u + 0x7FFFu + ((v.u >> 16) & 1u)) >> 16;
  return (unsigned short)r;
}
__device__ __forceinline__ float bf2f(unsigned s) {
  union { unsigned u; float f; } v; v.u = s << 16; return v.f;
}

// ---------------------------------------------------------------------------
// prep kernels
// ---------------------------------------------------------------------------
__global__ void ar_fill(const float* __restrict__ mels, float* __restrict__ ar) {
  int idx = blockIdx.x * 256 + threadIdx.x;
  if (idx >= T_STEPS * BB * DD) return;
  int d = idx % DD; int r = idx / DD; int b = r % BB; int t = r / BB;
  ar[idx] = (t == 0) ? 0.0f : mels[(b * DD + d) * T_STEPS + (t - 1)];
}

// w2frag[((kb*12+nt)*64+lane)*8+j] = bf16(out_w2[p][o]), p=nt*16+(lane&15),
// o=kb*32+8*(lane>>4)+j  (B-fragment layout for mfma_f32_16x16x32_bf16)
__global__ void w2frag_fill(const float* __restrict__ w2, unsigned short* __restrict__ wf) {
  int idx = blockIdx.x * 256 + threadIdx.x;
  if (idx >= 16 * 12 * 64 * 8) return;
  int j = idx & 7, lane = (idx >> 3) & 63, nt = (idx >> 9) % 12, kb = idx / 6144;
  int p = nt * 16 + (lane & 15);
  int o = kb * 32 + ((lane >> 4) << 3) + j;
  float v = (p < NPARAM) ? w2[p * OO + o] : 0.0f;
  wf[idx] = bf16rne(v);
}

__global__ void clear_hm(float* __restrict__ p) {
  int i = blockIdx.x * 256 + threadIdx.x;
  if (i < 16384) p[i] = 0.0f;
}

// fp32 -> bf16 conversion: dst[r*cols+c] = bf16(src[r*ld + off + c])
__global__ void f2b(const float* __restrict__ src, unsigned short* __restrict__ dst,
                    int total, int cols, int ld, int off) {
  int i = (blockIdx.x * 256 + threadIdx.x) * 4;
  if (i >= total) return;
  int r = i / cols, c = i % cols;
  float4 v = *(const float4*)&src[(size_t)r * ld + off + c];
  dst[i + 0] = bf16rne(v.x); dst[i + 1] = bf16rne(v.y);
  dst[i + 2] = bf16rne(v.z); dst[i + 3] = bf16rne(v.w);
}

// ---------------------------------------------------------------------------
// fp32 VALU GEMM (prenet only): C = relu(A @ B^T), handles K tails.
// ---------------------------------------------------------------------------
__global__ __launch_bounds__(256)
void gemm_nt(const float* __restrict__ A, int lda,
             const float* __restrict__ Bw, int ldb,
             float* __restrict__ C, int N, int K, int relu)
{
  __shared__ float As[32][64];
  __shared__ float Bs[32][64];
  const int tid = threadIdx.x;
  const int m0 = blockIdx.y * 64, n0 = blockIdx.x * 64;
  const int tm = tid & 15, tn = tid >> 4;
  float acc[4][4] = {{0.f,0.f,0.f,0.f},{0.f,0.f,0.f,0.f},{0.f,0.f,0.f,0.f},{0.f,0.f,0.f,0.f}};

  for (int k0 = 0; k0 < K; k0 += 32) {
#pragma unroll
    for (int half = 0; half < 2; ++half) {
      int mm = (tid >> 3) + half * 32;
      int kk = (tid & 7) * 4;
      const float* ap = &A[(size_t)(m0 + mm) * lda + k0 + kk];
      float4 av;
      if (k0 + kk + 3 < K) av = *(const float4*)ap;
      else {
        av.x = (k0 + kk + 0 < K) ? ap[0] : 0.f;
        av.y = (k0 + kk + 1 < K) ? ap[1] : 0.f;
        av.z = (k0 + kk + 2 < K) ? ap[2] : 0.f;
        av.w = (k0 + kk + 3 < K) ? ap[3] : 0.f;
      }
      As[kk + 0][mm] = av.x; As[kk + 1][mm] = av.y;
      As[kk + 2][mm] = av.z; As[kk + 3][mm] = av.w;
      const float* bp = &Bw[(size_t)(n0 + mm) * ldb + k0 + kk];
      float4 bv;
      if (k0 + kk + 3 < K) bv = *(const float4*)bp;
      else {
        bv.x = (k0 + kk + 0 < K) ? bp[0] : 0.f;
        bv.y = (k0 + kk + 1 < K) ? bp[1] : 0.f;
        bv.z = (k0 + kk + 2 < K) ? bp[2] : 0.f;
        bv.w = (k0 + kk + 3 < K) ? bp[3] : 0.f;
      }
      Bs[kk + 0][mm] = bv.x; Bs[kk + 1][mm] = bv.y;
      Bs[kk + 2][mm] = bv.z; Bs[kk + 3][mm] = bv.w;
    }
    __syncthreads();
#pragma unroll
    for (int kk = 0; kk < 32; ++kk) {
      float4 a4 = *(const float4*)&As[kk][tm * 4];
      float4 b4 = *(const float4*)&Bs[kk][tn * 4];
      float av[4] = {a4.x, a4.y, a4.z, a4.w};
      float bvv[4] = {b4.x, b4.y, b4.z, b4.w};
#pragma unroll
      for (int i = 0; i < 4; ++i)
#pragma unroll
        for (int j = 0; j < 4; ++j)
          acc[i][j] += av[i] * bvv[j];
    }
    __syncthreads();
  }
#pragma unroll
  for (int i = 0; i < 4; ++i) {
    int m = m0 + tm * 4 + i;
    float4 v;
    v.x = acc[i][0]; v.y = acc[i][1]; v.z = acc[i][2]; v.w = acc[i][3];
    if (relu) {
      v.x = fmaxf(v.x, 0.f); v.y = fmaxf(v.y, 0.f);
      v.z = fmaxf(v.z, 0.f); v.w = fmaxf(v.w, 0.f);
    }
    *(float4*)&C[(size_t)m * N + n0 + tn * 4] = v;
  }
}

// ---------------------------------------------------------------------------
// bf16 MFMA GEMM: C_fp32[m][n] = sum_k A[m][k]*B[n][k] (+bias1+bias2)(relu)
// A,B bf16 row-major. Tile 64x64, BK=64, 256 thr (4 waves); wave w owns a
// 16-col strip. Fragment conventions identical to the verified outnet kernel:
// A/B frag: lane holds idx=lane&15, k=8*(lane>>4)+j; C: row=(lane>>4)*4+r.
// ---------------------------------------------------------------------------
__global__ __launch_bounds__(256)
void gemm_mfma(const unsigned short* __restrict__ A, int lda,
               const unsigned short* __restrict__ B, int ldb,
               const float* __restrict__ bias1, const float* __restrict__ bias2,
               float* __restrict__ C, int N, int K, int relu)
{
  __shared__ unsigned short As[64 * GSTR];
  __shared__ unsigned short Bs[64 * GSTR];
  const int tid = threadIdx.x;
  const int lane = tid & 63, wv = tid >> 6;
  const int m0 = blockIdx.y * 64, n0 = blockIdx.x * 64;
  const int srow = tid >> 3, scol = (tid & 7) * 8;

  f32x4 acc[4];
#pragma unroll
  for (int m = 0; m < 4; ++m) acc[m] = (f32x4){0.f, 0.f, 0.f, 0.f};

  for (int k0 = 0; k0 < K; k0 += 64) {
    __syncthreads();
    *(float4*)&As[srow * GSTR + scol] =
        *(const float4*)&A[(size_t)(m0 + srow) * lda + k0 + scol];
    *(float4*)&As[(srow + 32) * GSTR + scol] =
        *(const float4*)&A[(size_t)(m0 + srow + 32) * lda + k0 + scol];
    *(float4*)&Bs[srow * GSTR + scol] =
        *(const float4*)&B[(size_t)(n0 + srow) * ldb + k0 + scol];
    *(float4*)&Bs[(srow + 32) * GSTR + scol] =
        *(const float4*)&B[(size_t)(n0 + srow + 32) * ldb + k0 + scol];
    __syncthreads();
#pragma unroll
    for (int ks = 0; ks < 2; ++ks) {
      const int kk = ks * 32 + 8 * (lane >> 4);
      s16x8 bfr = *(const s16x8*)&Bs[(wv * 16 + (lane & 15)) * GSTR + kk];
#pragma unroll
      for (int m = 0; m < 4; ++m) {
        s16x8 afr = *(const s16x8*)&As[(m * 16 + (lane & 15)) * GSTR + kk];
        acc[m] = __builtin_amdgcn_mfma_f32_16x16x32_bf16(afr, bfr, acc[m], 0, 0, 0);
      }
    }
  }
  const int cn = n0 + wv * 16 + (lane & 15);
  float bj = 0.f;
  if (bias1) bj += bias1[cn];
  if (bias2) bj += bias2[cn];
  const int rbase = m0 + (lane >> 4) * 4;
#pragma unroll
  for (int m = 0; m < 4; ++m)
#pragma unroll
    for (int r = 0; r < 4; ++r) {
      float v = acc[m][r] + bj;
      if (relu) v = fmaxf(v, 0.f);
      C[(size_t)(rbase + m * 16 + r) * N + cn] = v;
    }
}

// ---------------------------------------------------------------------------
// persistent sequential LSTM v4: tagged mailbox, 2 bf16 h + 32b tag per 8B
// word (single-RT sync: data IS the signal), pending-only re-poll.
// 128 blocks x 256 threads; block owns 4 j-units x 8 batches.
// Ring depth 4 (live span is only {t-1, t}); cleared once per launch.
// All blocks consume identical bf16(h), so the recurrence is consistent.
// ---------------------------------------------------------------------------
__global__ __launch_bounds__(LT)
void lstm_seq(const float* __restrict__ w_hh, const float* __restrict__ gates_x,
              unsigned short* __restrict__ h_allb, double* __restrict__ hm)
{
  __shared__ float wl[16][WSTR];
  __shared__ float hl[8][HSTR];
  __shared__ float hpub[32];
  __shared__ float gl[128];
  const int tid = threadIdx.x;
  const int blk = blockIdx.x;
  const int j0 = blk * 4;

  for (int r = 0; r < 16; ++r) {
    int g = r >> 2, jl = r & 3;
    const float* src = &w_hh[((size_t)(g * HH + j0 + jl)) * HH];
    for (int k = tid; k < HH; k += LT) wl[r][k] = src[k];
  }

  const int rg  = tid >> 6;          // gate (wave id)
  const int bg  = (tid >> 4) & 3;    // batch pair
  const int ksl = tid & 15;          // k-slice
  const int cjl = tid >> 3, cb = tid & 7;  // tid<32 update mapping
  float c_reg = 0.f;

  for (int t = 0; t < T_STEPS; ++t) {
    // prefetch this thread's 4 gate-x values (tid<32; independent of poll)
    float gxv[4] = {0.f, 0.f, 0.f, 0.f};
    if (tid < 32) {
      const float* gp = &gates_x[((size_t)t * BB + cb) * (4 * HH) + j0 + cjl];
#pragma unroll
      for (int g = 0; g < 4; ++g) gxv[g] = gp[g * HH];
    }

    // ---- acquire h[t-1]: poll tagged ring, pending-only reloads ----
    if (t == 0) {
      for (int i = tid; i < 8 * HSTR; i += LT) ((float*)hl)[i] = 0.f;
    } else {
      const double* ring = hm + (size_t)((t - 1) & 3) * 2048;
      unsigned pend = 0xFFu;
      do {
#pragma unroll
        for (int q = 0; q < 8; ++q) {
          if ((pend >> q) & 1u) {
            PairU w;
            w.d = __hip_atomic_load(&ring[q * 256 + tid], __ATOMIC_RELAXED, __HIP_MEMORY_SCOPE_AGENT);
            if (w.u[1] == (unsigned)t) {
              int s = q * 256 + tid;
              int sb = s >> 4, p = s & 15;
              int b = p & 7, j = sb * 4 + (p >> 3) * 2;
              hl[b][j]     = bf2f(w.u[0] & 0xFFFFu);
              hl[b][j + 1] = bf2f(w.u[0] >> 16);
              pend &= ~(1u << q);
            }
          }
        }
        if (pend) __builtin_amdgcn_s_sleep(1);
      } while (pend);
    }
    __syncthreads();

    // ---- partial matvec (k-slice per thread) ----
    float acc[4][2] = {{0.f,0.f},{0.f,0.f},{0.f,0.f},{0.f,0.f}};
#pragma unroll
    for (int i = 0; i < 8; ++i) {
      const int k = ksl * 4 + 64 * i;
      float4 h0 = *(const float4*)&hl[bg * 2][k];
      float4 h1 = *(const float4*)&hl[bg * 2 + 1][k];
#pragma unroll
      for (int rl = 0; rl < 4; ++rl) {
        float4 w = *(const float4*)&wl[rg * 4 + rl][k];
        acc[rl][0] += w.x * h0.x + w.y * h0.y + w.z * h0.z + w.w * h0.w;
        acc[rl][1] += w.x * h1.x + w.y * h1.y + w.z * h1.z + w.w * h1.w;
      }
    }
    // k-reduce across the 16 ksl lanes (same wave, same bg) via shuffles
#pragma unroll
    for (int rl = 0; rl < 4; ++rl)
#pragma unroll
      for (int bl = 0; bl < 2; ++bl) {
        float v = acc[rl][bl];
        v += __shfl_xor(v, 1); v += __shfl_xor(v, 2);
        v += __shfl_xor(v, 4); v += __shfl_xor(v, 8);
        if (ksl == 0) gl[(rg * 4 + rl) * 8 + bg * 2 + bl] = v;
      }
    __syncthreads();

    // ---- c/h update ----
    if (tid < 32) {
      float iv = gl[(0 * 4 + cjl) * 8 + cb] + gxv[0];
      float fv = gl[(1 * 4 + cjl) * 8 + cb] + gxv[1];
      float gv = gl[(2 * 4 + cjl) * 8 + cb] + gxv[2];
      float ov = gl[(3 * 4 + cjl) * 8 + cb] + gxv[3];
      float ct = sigmoidf_(fv) * c_reg + sigmoidf_(iv) * tanhf(gv);
      c_reg = ct;
      float h = sigmoidf_(ov) * tanhf(ct);
      hpub[cjl * 8 + cb] = h;
      h_allb[((size_t)t * BB + cb) * HH + j0 + cjl] = bf16rne(h);
    }
    __syncthreads();

    // ---- publish: one tagged 8B word per h-pair (data IS the signal) ----
    if (tid < 16) {
      int pb = tid & 7, pr = tid >> 3;
      float h0 = hpub[(pr * 2) * 8 + pb];
      float h1 = hpub[(pr * 2 + 1) * 8 + pb];
      PairU pv;
      pv.u[0] = (unsigned)bf16rne(h0) | ((unsigned)bf16rne(h1) << 16);
      pv.u[1] = (unsigned)(t + 1);
      __hip_atomic_store(&hm[(size_t)(t & 3) * 2048 + blk * 16 + tid], pv.d,
                         __ATOMIC_RELAXED, __HIP_MEMORY_SCOPE_AGENT);
    }
  }
}

// ---------------------------------------------------------------------------
// fused output net + emission, MFMA (verified layout). Block per (t,b).
// ---------------------------------------------------------------------------
__global__ __launch_bounds__(256)
void outnet(const float* __restrict__ hv, const float* __restrict__ zi,
            const unsigned short* __restrict__ w2frag, const float* __restrict__ b2,
            const float* __restrict__ mels, const int* __restrict__ inputs_len,
            float* __restrict__ em_out, float* __restrict__ lsn_out,
            float* __restrict__ lsp_out)
{
  __shared__ float hvs[OO];
  __shared__ float xts[96];
  __shared__ s16x8 Afr[2][256];
  __shared__ float pl[64 * PLS];
  const int tid = threadIdx.x;
  const int tb = blockIdx.x;
  const int t = tb >> 3, b = tb & 7;
  const int lane = tid & 63, wv = tid >> 6;

  if (tid < 128) *(float4*)&hvs[tid * 4] = *(const float4*)&hv[(size_t)tb * OO + tid * 4];
  if (tid < DD) xts[tid] = mels[(b * DD + tid) * T_STEPS + t];
  __syncthreads();

  const int n_state = wv * 16 + (lane & 15);
  const int osub = (lane >> 4) * 8;
  const float* zbase = zi + (size_t)(b * 64 + n_state) * OO;

  auto genA = [&](int kb, int buf) {
    int ob = kb * 32 + osub;
    float4 z0 = *(const float4*)&zbase[ob];
    float4 z1 = *(const float4*)&zbase[ob + 4];
    float4 h0 = *(const float4*)&hvs[ob];
    float4 h1 = *(const float4*)&hvs[ob + 4];
    s16x8 s;
    s[0] = bf16rne(fmaxf(z0.x + h0.x, 0.f));
    s[1] = bf16rne(fmaxf(z0.y + h0.y, 0.f));
    s[2] = bf16rne(fmaxf(z0.z + h0.z, 0.f));
    s[3] = bf16rne(fmaxf(z0.w + h0.w, 0.f));
    s[4] = bf16rne(fmaxf(z1.x + h1.x, 0.f));
    s[5] = bf16rne(fmaxf(z1.y + h1.y, 0.f));
    s[6] = bf16rne(fmaxf(z1.z + h1.z, 0.f));
    s[7] = bf16rne(fmaxf(z1.w + h1.w, 0.f));
    Afr[buf][tid] = s;
  };
  genA(0, 0);

  f32x4 acc[4][3];
#pragma unroll
  for (int m = 0; m < 4; ++m)
#pragma unroll
    for (int n = 0; n < 3; ++n) acc[m][n] = (f32x4){0.f, 0.f, 0.f, 0.f};

  const unsigned short* bfp = w2frag + ((size_t)(wv * 3) * 64 + lane) * 8;

  for (int kb = 0; kb < 16; ++kb) {
    __syncthreads();
    s16x8 bf[3];
#pragma unroll
    for (int ntl = 0; ntl < 3; ++ntl)
      bf[ntl] = *(const s16x8*)&bfp[(size_t)kb * 6144 + ntl * 512];
    if (kb < 15) genA(kb + 1, (kb + 1) & 1);
    s16x8 af[4];
#pragma unroll
    for (int m = 0; m < 4; ++m) af[m] = Afr[kb & 1][m * 64 + lane];
#pragma unroll
    for (int m = 0; m < 4; ++m)
#pragma unroll
      for (int ntl = 0; ntl < 3; ++ntl)
        acc[m][ntl] = __builtin_amdgcn_mfma_f32_16x16x32_bf16(af[m], bf[ntl], acc[m][ntl], 0, 0, 0);
  }

  const int prow4 = (lane >> 4) * 4;
#pragma unroll
  for (int ntl = 0; ntl < 3; ++ntl) {
    int p = (wv * 3 + ntl) * 16 + (lane & 15);
    if (p < NPARAM) {
      float bb2 = b2[p];
#pragma unroll
      for (int m = 0; m < 4; ++m)
#pragma unroll
        for (int r = 0; r < 4; ++r)
          pl[(m * 16 + prow4 + r) * PLS + p] = acc[m][ntl][r] + bb2;
    }
  }
  __syncthreads();

  const int ne = tid >> 2, dq = tid & 3;
  float s = 0.f;
  for (int d = dq * 20; d < dq * 20 + 20; ++d) {
    float mean = pl[ne * PLS + d];
    float sp   = pl[ne * PLS + 80 + d];
    float x = xts[d];
    float sf = (sp > 20.f) ? sp : log1pf(__expf(sp));
    float sd = fmaxf(sf, 0.001f);
    float zz = (x - mean) / sd;
    s += -0.5f * zz * zz - __logf(sd) - 0.91893853320467274f;
  }
  s += __shfl_xor(s, 1);
  s += __shfl_xor(s, 2);
  if (dq == 0) {
    int ilen = inputs_len[b];
    em_out[(size_t)tb * NSTATE + ne] = (ne < ilen) ? s : 0.f;
    float tv = pl[ne * PLS + 160];
    lsp_out[(size_t)tb * NSTATE + ne] = __logf(fmaxf(sigmoidf_(tv), 1e-4f));
    lsn_out[(size_t)tb * NSTATE + ne] = __logf(fmaxf(sigmoidf_(-tv), 1e-4f));
  }
}

// ---------------------------------------------------------------------------
// sequential HMM forward scan: 1 block, wave per batch, t+1 load prefetch.
// ---------------------------------------------------------------------------
__global__ __launch_bounds__(512)
void hmm_scan(const float* __restrict__ em, const float* __restrict__ lsn,
              const float* __restrict__ lsp, const int* __restrict__ inputs_len,
              const int* __restrict__ mel_lens, float* __restrict__ out)
{
  const int tid = threadIdx.x;
  const int b = tid >> 6, n = tid & 63;
  const int ilen = inputs_len[b], mlen = mel_lens[b];
  const bool mask = n < ilen;
  const size_t stepo = (size_t)BB * NSTATE;
  const size_t base = (size_t)b * NSTATE + n;
  float alpha = 0.f, slc = 0.f, la = NEG_INF_F, llsp = 0.f;
  float e = em[base], ln_ = lsn[base], lp_ = lsp[base];

  for (int t = 0; t < T_STEPS; ++t) {
    float en = 0.f, lnn = 0.f, lpn = 0.f;
    if (t + 1 < T_STEPS) {
      size_t nb = base + (size_t)(t + 1) * stepo;
      en = em[nb]; lnn = lsn[nb]; lpn = lsp[nb];
    }
    float at;
    if (t == 0) {
      at = ((n == 0) ? 0.f : NEG_INF_F) + e;
    } else {
      float stay = alpha + ln_;
      float lvs = alpha + lp_;
      float lv = __shfl_up(lvs, 1, 64);
      if (n == 0) lv = NEG_INF_F;
      float mx = fmaxf(stay, lv), mn = fminf(stay, lv);
      float tt = mask ? (mx + log1pf(__expf(mn - mx))) : NEG_INF_F;
      at = e + tt;
    }
    float m = at;
#pragma unroll
    for (int off = 1; off < 64; off <<= 1) m = fmaxf(m, __shfl_xor(m, off));
    float es = __expf(at - m);
#pragma unroll
    for (int off = 1; off < 64; off <<= 1) es += __shfl_xor(es, off);
    float logc = m + __logf(es);
    alpha = at - logc;
    if (t < mlen) slc += logc;
    if (t == mlen - 1) { la = mask ? alpha : NEG_INF_F; llsp = lp_; }
    e = en; ln_ = lnn; lp_ = lpn;
  }

  float v = la + ((n == ilen - 1) ? llsp : NEG_INF_F);
  float m = v;
#pragma unroll
  for (int off = 1; off < 64; off <<= 1) m = fmaxf(m, __shfl_xor(m, off));
  float es = __expf(v - m);
#pragma unroll
  for (int off = 1; off < 64; off <<= 1) es += __shfl_xor(es, off);
  float sfin = m + __logf(es);
  if (n == 0) out[b] = slc + sfin;
}

// ---------------------------------------------------------------------------
extern "C" void kernel_launch(void* const* d_in, const int* in_sizes, int n_in,
                              void* d_out, int out_size, void* d_ws, size_t ws_size,
                              hipStream_t stream)
{
  const float* inputs    = (const float*)d_in[0];
  const float* mels      = (const float*)d_in[1];
  const float* prenet_w1 = (const float*)d_in[2];
  const float* prenet_w2 = (const float*)d_in[3];
  const float* w_ih      = (const float*)d_in[4];
  const float* w_hh      = (const float*)d_in[5];
  const float* b_ih      = (const float*)d_in[6];
  const float* b_hh      = (const float*)d_in[7];
  const float* out_w1    = (const float*)d_in[8];
  const float* out_b1    = (const float*)d_in[9];
  const float* out_w2    = (const float*)d_in[10];
  const float* out_b2    = (const float*)d_in[11];
  const int* inputs_len  = (const int*)d_in[12];
  const int* mel_lens    = (const int*)d_in[13];

  float* ws = (float*)d_ws;
  // layout (floats). Overlay zone [0, 688128) = ar+p1, reused for bf16 weights
  // AFTER the prenet GEMMs are done.
  float* ar      = ws;                        // 163840
  float* p1      = ws + 163840;               // 524288
  float* p2      = ws + 688128;               // 524288
  float* gates_x = ws + 1212416;              // 4194304
  float* zi      = ws + 5406720;              // 262144  ([b*64+n][o])
  unsigned short* w2frag = (unsigned short*)(ws + 5668864);  // 98304 sh (49152 fl)
  float* hv      = ws + 5718016;              // 1048576
  float* em      = ws + 6766592;              // 131072
  float* lsn     = ws + 6897664;              // 131072
  float* lsp     = ws + 7028736;              // 131072
  double* hm     = (double*)(ws + 7159808);   // 8192 doubles (16384 fl)
  unsigned short* p2b    = (unsigned short*)(ws + 7176192);  // 524288 sh (262144 fl)
  unsigned short* h_allb = (unsigned short*)(ws + 7438336);  // 1048576 sh (524288 fl)
  // overlay (valid after prenet):
  unsigned short* w_ihb   = (unsigned short*)(ws + 0);       // 524288 sh
  unsigned short* w1hb    = (unsigned short*)(ws + 262144);  // 262144 sh
  unsigned short* w1eb    = (unsigned short*)(ws + 393216);  // 262144 sh
  unsigned short* inputsb = (unsigned short*)(ws + 524288);  // 262144 sh

  // time-parallel precompute
  ar_fill<<<640, 256, 0, stream>>>(mels, ar);
  w2frag_fill<<<384, 256, 0, stream>>>(out_w2, w2frag);
  clear_hm<<<64, 256, 0, stream>>>((float*)hm);

  // prenet (fp32 VALU GEMM)
  gemm_nt<<<dim3(4, 32), 256, 0, stream>>>(ar, DD, prenet_w1, DD, p1, PP, DD, 1);
  gemm_nt<<<dim3(4, 32), 256, 0, stream>>>(p1, PP, prenet_w2, PP, p2, PP, PP, 1);

  // bf16 conversions (ar/p1 now dead -> overlay)
  f2b<<<512, 256, 0, stream>>>(w_ih,   w_ihb,   524288, 256, 256,  0);
  f2b<<<256, 256, 0, stream>>>(out_w1, w1hb,    262144, 512, 1024, 0);
  f2b<<<256, 256, 0, stream>>>(out_w1, w1eb,    262144, 512, 1024, 512);
  f2b<<<256, 256, 0, stream>>>(inputs, inputsb, 262144, 512, 512,  0);
  f2b<<<512, 256, 0, stream>>>(p2,     p2b,     524288, 256, 256,  0);

  // gates_x = p2 @ w_ih^T + b_ih + b_hh   M=2048 N=2048 K=256
  gemm_mfma<<<dim3(32, 32), 256, 0, stream>>>(p2b, 256, w_ihb, 256,
                                              b_ih, b_hh, gates_x, 2048, 256, 0);
  // zi = inputs @ W1_e^T + b1             M=512 N=512 K=512
  gemm_mfma<<<dim3(8, 8), 256, 0, stream>>>(inputsb, 512, w1eb, 512,
                                            out_b1, nullptr, zi, 512, 512, 0);

  // sequential LSTM (tagged bf16-pair mailbox)
  lstm_seq<<<LB, LT, 0, stream>>>(w_hh, gates_x, h_allb, hm);

  // hv = h @ W1_h^T                       M=2048 N=512 K=512
  gemm_mfma<<<dim3(8, 32), 256, 0, stream>>>(h_allb, 512, w1hb, 512,
                                             nullptr, nullptr, hv, 512, 512, 0);

  // fused output net + emission (MFMA)
  outnet<<<2048, 256, 0, stream>>>(hv, zi, w2frag, out_b2, mels, inputs_len,
                                   em, lsn, lsp);

  // sequential HMM scan
  hmm_scan<<<1, 512, 0, stream>>>(em, lsn, lsp, inputs_len, mel_lens, (float*)d_out);
}

// Round 5
// 1574.155 us; speedup vs baseline: 1.1457x; 1.1190x over previous
//
#include <hip/hip_runtime.h>
#include <math.h>

// Problem constants
#define T_STEPS 256
#define BB 8
#define NSTATE 64
#define DD 80
#define PP 256
#define HH 512
#define OO 512
#define NPARAM 161   // 2*D+1
#define PLS 171      // padded row stride for params in LDS (bank spread)
#define NEG_INF_F (-1000000.0f)

// lstm config
#define LB 128       // lstm blocks (4 j-units each)
#define LT 256       // lstm threads per block
#define HSTR 516     // hl row stride (floats) — bank spread
#define WSTR 516     // wl row stride

#define GSTR 88      // gemm_mfma LDS row stride in ushorts

typedef __attribute__((ext_vector_type(8))) short s16x8;
typedef __attribute__((ext_vector_type(4))) float f32x4;

union PairU { double d; float f[2]; unsigned u[2]; };

__device__ __forceinline__ float sigmoidf_(float x) { return 1.0f / (1.0f + __expf(-x)); }
__device__ __forceinline__ unsigned short bf16rne(float x) {
  union { float f; unsigned u; } v; v.f = x;
  unsigned r = (v.u + 0x7FFFu + ((v.u >> 16) & 1u)) >> 16;
  return (unsigned short)r;
}
__device__ __forceinline__ float bf2f(unsigned s) {
  union { unsigned u; float f; } v; v.u = s << 16; return v.f;
}

// ---------------------------------------------------------------------------
// prep kernels
// ---------------------------------------------------------------------------
__global__ void ar_fill(const float* __restrict__ mels, float* __restrict__ ar) {
  int idx = blockIdx.x * 256 + threadIdx.x;
  if (idx >= T_STEPS * BB * DD) return;
  int d = idx % DD; int r = idx / DD; int b = r % BB; int t = r / BB;
  ar[idx] = (t == 0) ? 0.0f : mels[(b * DD + d) * T_STEPS + (t - 1)];
}

// w2frag: B-fragment layout for mfma_f32_16x16x32_bf16 (verified in outnet)
__global__ void w2frag_fill(const float* __restrict__ w2, unsigned short* __restrict__ wf) {
  int idx = blockIdx.x * 256 + threadIdx.x;
  if (idx >= 16 * 12 * 64 * 8) return;
  int j = idx & 7, lane = (idx >> 3) & 63, nt = (idx >> 9) % 12, kb = idx / 6144;
  int p = nt * 16 + (lane & 15);
  int o = kb * 32 + ((lane >> 4) << 3) + j;
  float v = (p < NPARAM) ? w2[p * OO + o] : 0.0f;
  wf[idx] = bf16rne(v);
}

__global__ void clear_hm(float* __restrict__ p) {
  int i = blockIdx.x * 256 + threadIdx.x;
  if (i < 16384) p[i] = 0.0f;
}

// fp32 -> bf16 conversion: dst[r*cols+c] = bf16(src[r*ld + off + c])
__global__ void f2b(const float* __restrict__ src, unsigned short* __restrict__ dst,
                    int total, int cols, int ld, int off) {
  int i = (blockIdx.x * 256 + threadIdx.x) * 4;
  if (i >= total) return;
  int r = i / cols, c = i % cols;
  float4 v = *(const float4*)&src[(size_t)r * ld + off + c];
  dst[i + 0] = bf16rne(v.x); dst[i + 1] = bf16rne(v.y);
  dst[i + 2] = bf16rne(v.z); dst[i + 3] = bf16rne(v.w);
}

// ---------------------------------------------------------------------------
// fp32 VALU GEMM (prenet only): C = relu(A @ B^T), handles K tails.
// ---------------------------------------------------------------------------
__global__ __launch_bounds__(256)
void gemm_nt(const float* __restrict__ A, int lda,
             const float* __restrict__ Bw, int ldb,
             float* __restrict__ C, int N, int K, int relu)
{
  __shared__ float As[32][64];
  __shared__ float Bs[32][64];
  const int tid = threadIdx.x;
  const int m0 = blockIdx.y * 64, n0 = blockIdx.x * 64;
  const int tm = tid & 15, tn = tid >> 4;
  float acc[4][4] = {{0.f,0.f,0.f,0.f},{0.f,0.f,0.f,0.f},{0.f,0.f,0.f,0.f},{0.f,0.f,0.f,0.f}};

  for (int k0 = 0; k0 < K; k0 += 32) {
#pragma unroll
    for (int half = 0; half < 2; ++half) {
      int mm = (tid >> 3) + half * 32;
      int kk = (tid & 7) * 4;
      const float* ap = &A[(size_t)(m0 + mm) * lda + k0 + kk];
      float4 av;
      if (k0 + kk + 3 < K) av = *(const float4*)ap;
      else {
        av.x = (k0 + kk + 0 < K) ? ap[0] : 0.f;
        av.y = (k0 + kk + 1 < K) ? ap[1] : 0.f;
        av.z = (k0 + kk + 2 < K) ? ap[2] : 0.f;
        av.w = (k0 + kk + 3 < K) ? ap[3] : 0.f;
      }
      As[kk + 0][mm] = av.x; As[kk + 1][mm] = av.y;
      As[kk + 2][mm] = av.z; As[kk + 3][mm] = av.w;
      const float* bp = &Bw[(size_t)(n0 + mm) * ldb + k0 + kk];
      float4 bv;
      if (k0 + kk + 3 < K) bv = *(const float4*)bp;
      else {
        bv.x = (k0 + kk + 0 < K) ? bp[0] : 0.f;
        bv.y = (k0 + kk + 1 < K) ? bp[1] : 0.f;
        bv.z = (k0 + kk + 2 < K) ? bp[2] : 0.f;
        bv.w = (k0 + kk + 3 < K) ? bp[3] : 0.f;
      }
      Bs[kk + 0][mm] = bv.x; Bs[kk + 1][mm] = bv.y;
      Bs[kk + 2][mm] = bv.z; Bs[kk + 3][mm] = bv.w;
    }
    __syncthreads();
#pragma unroll
    for (int kk = 0; kk < 32; ++kk) {
      float4 a4 = *(const float4*)&As[kk][tm * 4];
      float4 b4 = *(const float4*)&Bs[kk][tn * 4];
      float av[4] = {a4.x, a4.y, a4.z, a4.w};
      float bvv[4] = {b4.x, b4.y, b4.z, b4.w};
#pragma unroll
      for (int i = 0; i < 4; ++i)
#pragma unroll
        for (int j = 0; j < 4; ++j)
          acc[i][j] += av[i] * bvv[j];
    }
    __syncthreads();
  }
#pragma unroll
  for (int i = 0; i < 4; ++i) {
    int m = m0 + tm * 4 + i;
    float4 v;
    v.x = acc[i][0]; v.y = acc[i][1]; v.z = acc[i][2]; v.w = acc[i][3];
    if (relu) {
      v.x = fmaxf(v.x, 0.f); v.y = fmaxf(v.y, 0.f);
      v.z = fmaxf(v.z, 0.f); v.w = fmaxf(v.w, 0.f);
    }
    *(float4*)&C[(size_t)m * N + n0 + tn * 4] = v;
  }
}

// ---------------------------------------------------------------------------
// bf16 MFMA GEMM (fragment conventions verified by outnet)
// ---------------------------------------------------------------------------
__global__ __launch_bounds__(256)
void gemm_mfma(const unsigned short* __restrict__ A, int lda,
               const unsigned short* __restrict__ B, int ldb,
               const float* __restrict__ bias1, const float* __restrict__ bias2,
               float* __restrict__ C, int N, int K, int relu)
{
  __shared__ unsigned short As[64 * GSTR];
  __shared__ unsigned short Bs[64 * GSTR];
  const int tid = threadIdx.x;
  const int lane = tid & 63, wv = tid >> 6;
  const int m0 = blockIdx.y * 64, n0 = blockIdx.x * 64;
  const int srow = tid >> 3, scol = (tid & 7) * 8;

  f32x4 acc[4];
#pragma unroll
  for (int m = 0; m < 4; ++m) acc[m] = (f32x4){0.f, 0.f, 0.f, 0.f};

  for (int k0 = 0; k0 < K; k0 += 64) {
    __syncthreads();
    *(float4*)&As[srow * GSTR + scol] =
        *(const float4*)&A[(size_t)(m0 + srow) * lda + k0 + scol];
    *(float4*)&As[(srow + 32) * GSTR + scol] =
        *(const float4*)&A[(size_t)(m0 + srow + 32) * lda + k0 + scol];
    *(float4*)&Bs[srow * GSTR + scol] =
        *(const float4*)&B[(size_t)(n0 + srow) * ldb + k0 + scol];
    *(float4*)&Bs[(srow + 32) * GSTR + scol] =
        *(const float4*)&B[(size_t)(n0 + srow + 32) * ldb + k0 + scol];
    __syncthreads();
#pragma unroll
    for (int ks = 0; ks < 2; ++ks) {
      const int kk = ks * 32 + 8 * (lane >> 4);
      s16x8 bfr = *(const s16x8*)&Bs[(wv * 16 + (lane & 15)) * GSTR + kk];
#pragma unroll
      for (int m = 0; m < 4; ++m) {
        s16x8 afr = *(const s16x8*)&As[(m * 16 + (lane & 15)) * GSTR + kk];
        acc[m] = __builtin_amdgcn_mfma_f32_16x16x32_bf16(afr, bfr, acc[m], 0, 0, 0);
      }
    }
  }
  const int cn = n0 + wv * 16 + (lane & 15);
  float bj = 0.f;
  if (bias1) bj += bias1[cn];
  if (bias2) bj += bias2[cn];
  const int rbase = m0 + (lane >> 4) * 4;
#pragma unroll
  for (int m = 0; m < 4; ++m)
#pragma unroll
    for (int r = 0; r < 4; ++r) {
      float v = acc[m][r] + bj;
      if (relu) v = fmaxf(v, 0.f);
      C[(size_t)(rbase + m * 16 + r) * N + cn] = v;
    }
}

// ---------------------------------------------------------------------------
// persistent sequential LSTM v5: tagged words (v4 format, verified) + R2-style
// two-phase acquire: wave0 polls ONLY word-0 of each producer (128 words, one
// RT/round, zero traffic from other threads), then ALL threads bulk-load once
// with tag verification (stragglers ~never: sibling words issue in the same
// wave-store instruction as word 0).
// Producer: no drain barrier, no flag store — tag rides with the data; pair
// packing via __shfl_xor in-register.
// ---------------------------------------------------------------------------
__global__ __launch_bounds__(LT)
void lstm_seq(const float* __restrict__ w_hh, const float* __restrict__ gates_x,
              unsigned short* __restrict__ h_allb, double* __restrict__ hm)
{
  __shared__ float wl[16][WSTR];
  __shared__ float hl[8][HSTR];
  __shared__ float gl[128];
  const int tid = threadIdx.x;
  const int blk = blockIdx.x;
  const int j0 = blk * 4;

  for (int r = 0; r < 16; ++r) {
    int g = r >> 2, jl = r & 3;
    const float* src = &w_hh[((size_t)(g * HH + j0 + jl)) * HH];
    for (int k = tid; k < HH; k += LT) wl[r][k] = src[k];
  }

  const int rg  = tid >> 6;          // gate (wave id)
  const int bg  = (tid >> 4) & 3;    // batch pair
  const int ksl = tid & 15;          // k-slice
  const int cjl = tid >> 3, cb = tid & 7;  // tid<32 update mapping
  float c_reg = 0.f;

  for (int t = 0; t < T_STEPS; ++t) {
    // prefetch this thread's 4 gate-x values (independent of the poll)
    float gxv[4] = {0.f, 0.f, 0.f, 0.f};
    if (tid < 32) {
      const float* gp = &gates_x[((size_t)t * BB + cb) * (4 * HH) + j0 + cjl];
#pragma unroll
      for (int g = 0; g < 4; ++g) gxv[g] = gp[g * HH];
    }

    if (t == 0) {
      for (int i = tid; i < 8 * HSTR; i += LT) ((float*)hl)[i] = 0.f;
      __syncthreads();
    } else {
      const double* ring = hm + (size_t)((t - 1) & 3) * 2048;
      // phase 1: wave0 polls word-0 tag of each of 128 producers
      if (tid < 64) {
        for (;;) {
          PairU a, c;
          a.d = __hip_atomic_load(&ring[(size_t)tid * 16], __ATOMIC_RELAXED, __HIP_MEMORY_SCOPE_AGENT);
          c.d = __hip_atomic_load(&ring[(size_t)(tid + 64) * 16], __ATOMIC_RELAXED, __HIP_MEMORY_SCOPE_AGENT);
          if (__all(a.u[1] == (unsigned)t && c.u[1] == (unsigned)t)) break;
          __builtin_amdgcn_s_sleep(1);
        }
      }
      __syncthreads();
      // phase 2: bulk load once, verify tags (straggler rounds expected: 0)
      unsigned pend = 0xFFu;
      do {
#pragma unroll
        for (int q = 0; q < 8; ++q) {
          if ((pend >> q) & 1u) {
            PairU w;
            w.d = __hip_atomic_load(&ring[q * 256 + tid], __ATOMIC_RELAXED, __HIP_MEMORY_SCOPE_AGENT);
            if (w.u[1] == (unsigned)t) {
              int s = q * 256 + tid;
              int sb = s >> 4, p = s & 15;
              int b = p & 7, j = sb * 4 + (p >> 3) * 2;
              hl[b][j]     = bf2f(w.u[0] & 0xFFFFu);
              hl[b][j + 1] = bf2f(w.u[0] >> 16);
              pend &= ~(1u << q);
            }
          }
        }
        if (pend) __builtin_amdgcn_s_sleep(1);
      } while (pend);
      __syncthreads();
    }

    // ---- partial matvec (k-slice per thread) ----
    float acc[4][2] = {{0.f,0.f},{0.f,0.f},{0.f,0.f},{0.f,0.f}};
#pragma unroll
    for (int i = 0; i < 8; ++i) {
      const int k = ksl * 4 + 64 * i;
      float4 h0 = *(const float4*)&hl[bg * 2][k];
      float4 h1 = *(const float4*)&hl[bg * 2 + 1][k];
#pragma unroll
      for (int rl = 0; rl < 4; ++rl) {
        float4 w = *(const float4*)&wl[rg * 4 + rl][k];
        acc[rl][0] += w.x * h0.x + w.y * h0.y + w.z * h0.z + w.w * h0.w;
        acc[rl][1] += w.x * h1.x + w.y * h1.y + w.z * h1.z + w.w * h1.w;
      }
    }
    // k-reduce across 16 ksl lanes (same wave) via shuffles
#pragma unroll
    for (int rl = 0; rl < 4; ++rl)
#pragma unroll
      for (int bl = 0; bl < 2; ++bl) {
        float v = acc[rl][bl];
        v += __shfl_xor(v, 1); v += __shfl_xor(v, 2);
        v += __shfl_xor(v, 4); v += __shfl_xor(v, 8);
        if (ksl == 0) gl[(rg * 4 + rl) * 8 + bg * 2 + bl] = v;
      }
    __syncthreads();

    // ---- c/h update + publish (tag rides with data; no drain, no flag) ----
    if (tid < 32) {
      float iv = gl[(0 * 4 + cjl) * 8 + cb] + gxv[0];
      float fv = gl[(1 * 4 + cjl) * 8 + cb] + gxv[1];
      float gv = gl[(2 * 4 + cjl) * 8 + cb] + gxv[2];
      float ov = gl[(3 * 4 + cjl) * 8 + cb] + gxv[3];
      float ct = sigmoidf_(fv) * c_reg + sigmoidf_(iv) * tanhf(gv);
      c_reg = ct;
      float h = sigmoidf_(ov) * tanhf(ct);
      float hp = __shfl_xor(h, 8);     // partner j (cjl^1), same batch
      h_allb[((size_t)t * BB + cb) * HH + j0 + cjl] = bf16rne(h);
      if ((cjl & 1) == 0) {
        PairU pv;
        pv.u[0] = (unsigned)bf16rne(h) | ((unsigned)bf16rne(hp) << 16);
        pv.u[1] = (unsigned)(t + 1);
        int widx = (cjl >> 1) * 8 + cb;
        __hip_atomic_store(&hm[(size_t)(t & 3) * 2048 + blk * 16 + widx], pv.d,
                           __ATOMIC_RELAXED, __HIP_MEMORY_SCOPE_AGENT);
      }
    }
    // no trailing barrier: hl/gl rewrites next iter are ordered by the
    // phase-1/phase-2 barriers (all threads passed this step's gl barrier).
  }
}

// ---------------------------------------------------------------------------
// fused output net + emission, MFMA (verified layout). Block per (t,b).
// ---------------------------------------------------------------------------
__global__ __launch_bounds__(256)
void outnet(const float* __restrict__ hv, const float* __restrict__ zi,
            const unsigned short* __restrict__ w2frag, const float* __restrict__ b2,
            const float* __restrict__ mels, const int* __restrict__ inputs_len,
            float* __restrict__ em_out, float* __restrict__ lsn_out,
            float* __restrict__ lsp_out)
{
  __shared__ float hvs[OO];
  __shared__ float xts[96];
  __shared__ s16x8 Afr[2][256];
  __shared__ float pl[64 * PLS];
  const int tid = threadIdx.x;
  const int tb = blockIdx.x;
  const int t = tb >> 3, b = tb & 7;
  const int lane = tid & 63, wv = tid >> 6;

  if (tid < 128) *(float4*)&hvs[tid * 4] = *(const float4*)&hv[(size_t)tb * OO + tid * 4];
  if (tid < DD) xts[tid] = mels[(b * DD + tid) * T_STEPS + t];
  __syncthreads();

  const int n_state = wv * 16 + (lane & 15);
  const int osub = (lane >> 4) * 8;
  const float* zbase = zi + (size_t)(b * 64 + n_state) * OO;

  auto genA = [&](int kb, int buf) {
    int ob = kb * 32 + osub;
    float4 z0 = *(const float4*)&zbase[ob];
    float4 z1 = *(const float4*)&zbase[ob + 4];
    float4 h0 = *(const float4*)&hvs[ob];
    float4 h1 = *(const float4*)&hvs[ob + 4];
    s16x8 s;
    s[0] = bf16rne(fmaxf(z0.x + h0.x, 0.f));
    s[1] = bf16rne(fmaxf(z0.y + h0.y, 0.f));
    s[2] = bf16rne(fmaxf(z0.z + h0.z, 0.f));
    s[3] = bf16rne(fmaxf(z0.w + h0.w, 0.f));
    s[4] = bf16rne(fmaxf(z1.x + h1.x, 0.f));
    s[5] = bf16rne(fmaxf(z1.y + h1.y, 0.f));
    s[6] = bf16rne(fmaxf(z1.z + h1.z, 0.f));
    s[7] = bf16rne(fmaxf(z1.w + h1.w, 0.f));
    Afr[buf][tid] = s;
  };
  genA(0, 0);

  f32x4 acc[4][3];
#pragma unroll
  for (int m = 0; m < 4; ++m)
#pragma unroll
    for (int n = 0; n < 3; ++n) acc[m][n] = (f32x4){0.f, 0.f, 0.f, 0.f};

  const unsigned short* bfp = w2frag + ((size_t)(wv * 3) * 64 + lane) * 8;

  for (int kb = 0; kb < 16; ++kb) {
    __syncthreads();
    s16x8 bf[3];
#pragma unroll
    for (int ntl = 0; ntl < 3; ++ntl)
      bf[ntl] = *(const s16x8*)&bfp[(size_t)kb * 6144 + ntl * 512];
    if (kb < 15) genA(kb + 1, (kb + 1) & 1);
    s16x8 af[4];
#pragma unroll
    for (int m = 0; m < 4; ++m) af[m] = Afr[kb & 1][m * 64 + lane];
#pragma unroll
    for (int m = 0; m < 4; ++m)
#pragma unroll
      for (int ntl = 0; ntl < 3; ++ntl)
        acc[m][ntl] = __builtin_amdgcn_mfma_f32_16x16x32_bf16(af[m], bf[ntl], acc[m][ntl], 0, 0, 0);
  }

  const int prow4 = (lane >> 4) * 4;
#pragma unroll
  for (int ntl = 0; ntl < 3; ++ntl) {
    int p = (wv * 3 + ntl) * 16 + (lane & 15);
    if (p < NPARAM) {
      float bb2 = b2[p];
#pragma unroll
      for (int m = 0; m < 4; ++m)
#pragma unroll
        for (int r = 0; r < 4; ++r)
          pl[(m * 16 + prow4 + r) * PLS + p] = acc[m][ntl][r] + bb2;
    }
  }
  __syncthreads();

  const int ne = tid >> 2, dq = tid & 3;
  float s = 0.f;
  for (int d = dq * 20; d < dq * 20 + 20; ++d) {
    float mean = pl[ne * PLS + d];
    float sp   = pl[ne * PLS + 80 + d];
    float x = xts[d];
    float sf = (sp > 20.f) ? sp : log1pf(__expf(sp));
    float sd = fmaxf(sf, 0.001f);
    float zz = (x - mean) / sd;
    s += -0.5f * zz * zz - __logf(sd) - 0.91893853320467274f;
  }
  s += __shfl_xor(s, 1);
  s += __shfl_xor(s, 2);
  if (dq == 0) {
    int ilen = inputs_len[b];
    em_out[(size_t)tb * NSTATE + ne] = (ne < ilen) ? s : 0.f;
    float tv = pl[ne * PLS + 160];
    lsp_out[(size_t)tb * NSTATE + ne] = __logf(fmaxf(sigmoidf_(tv), 1e-4f));
    lsn_out[(size_t)tb * NSTATE + ne] = __logf(fmaxf(sigmoidf_(-tv), 1e-4f));
  }
}

// ---------------------------------------------------------------------------
// sequential HMM forward scan: 1 block, wave per batch, t+1 load prefetch.
// ---------------------------------------------------------------------------
__global__ __launch_bounds__(512)
void hmm_scan(const float* __restrict__ em, const float* __restrict__ lsn,
              const float* __restrict__ lsp, const int* __restrict__ inputs_len,
              const int* __restrict__ mel_lens, float* __restrict__ out)
{
  const int tid = threadIdx.x;
  const int b = tid >> 6, n = tid & 63;
  const int ilen = inputs_len[b], mlen = mel_lens[b];
  const bool mask = n < ilen;
  const size_t stepo = (size_t)BB * NSTATE;
  const size_t base = (size_t)b * NSTATE + n;
  float alpha = 0.f, slc = 0.f, la = NEG_INF_F, llsp = 0.f;
  float e = em[base], ln_ = lsn[base], lp_ = lsp[base];

  for (int t = 0; t < T_STEPS; ++t) {
    float en = 0.f, lnn = 0.f, lpn = 0.f;
    if (t + 1 < T_STEPS) {
      size_t nb = base + (size_t)(t + 1) * stepo;
      en = em[nb]; lnn = lsn[nb]; lpn = lsp[nb];
    }
    float at;
    if (t == 0) {
      at = ((n == 0) ? 0.f : NEG_INF_F) + e;
    } else {
      float stay = alpha + ln_;
      float lvs = alpha + lp_;
      float lv = __shfl_up(lvs, 1, 64);
      if (n == 0) lv = NEG_INF_F;
      float mx = fmaxf(stay, lv), mn = fminf(stay, lv);
      float tt = mask ? (mx + log1pf(__expf(mn - mx))) : NEG_INF_F;
      at = e + tt;
    }
    float m = at;
#pragma unroll
    for (int off = 1; off < 64; off <<= 1) m = fmaxf(m, __shfl_xor(m, off));
    float es = __expf(at - m);
#pragma unroll
    for (int off = 1; off < 64; off <<= 1) es += __shfl_xor(es, off);
    float logc = m + __logf(es);
    alpha = at - logc;
    if (t < mlen) slc += logc;
    if (t == mlen - 1) { la = mask ? alpha : NEG_INF_F; llsp = lp_; }
    e = en; ln_ = lnn; lp_ = lpn;
  }

  float v = la + ((n == ilen - 1) ? llsp : NEG_INF_F);
  float m = v;
#pragma unroll
  for (int off = 1; off < 64; off <<= 1) m = fmaxf(m, __shfl_xor(m, off));
  float es = __expf(v - m);
#pragma unroll
  for (int off = 1; off < 64; off <<= 1) es += __shfl_xor(es, off);
  float sfin = m + __logf(es);
  if (n == 0) out[b] = slc + sfin;
}

// ---------------------------------------------------------------------------
extern "C" void kernel_launch(void* const* d_in, const int* in_sizes, int n_in,
                              void* d_out, int out_size, void* d_ws, size_t ws_size,
                              hipStream_t stream)
{
  const float* inputs    = (const float*)d_in[0];
  const float* mels      = (const float*)d_in[1];
  const float* prenet_w1 = (const float*)d_in[2];
  const float* prenet_w2 = (const float*)d_in[3];
  const float* w_ih      = (const float*)d_in[4];
  const float* w_hh      = (const float*)d_in[5];
  const float* b_ih      = (const float*)d_in[6];
  const float* b_hh      = (const float*)d_in[7];
  const float* out_w1    = (const float*)d_in[8];
  const float* out_b1    = (const float*)d_in[9];
  const float* out_w2    = (const float*)d_in[10];
  const float* out_b2    = (const float*)d_in[11];
  const int* inputs_len  = (const int*)d_in[12];
  const int* mel_lens    = (const int*)d_in[13];

  float* ws = (float*)d_ws;
  float* ar      = ws;                        // 163840
  float* p1      = ws + 163840;               // 524288
  float* p2      = ws + 688128;               // 524288
  float* gates_x = ws + 1212416;              // 4194304
  float* zi      = ws + 5406720;              // 262144  ([b*64+n][o])
  unsigned short* w2frag = (unsigned short*)(ws + 5668864);  // 98304 sh
  float* hv      = ws + 5718016;              // 1048576
  float* em      = ws + 6766592;              // 131072
  float* lsn     = ws + 6897664;              // 131072
  float* lsp     = ws + 7028736;              // 131072
  double* hm     = (double*)(ws + 7159808);   // 8192 doubles
  unsigned short* p2b    = (unsigned short*)(ws + 7176192);  // 524288 sh
  unsigned short* h_allb = (unsigned short*)(ws + 7438336);  // 1048576 sh
  // overlay (valid after prenet):
  unsigned short* w_ihb   = (unsigned short*)(ws + 0);       // 524288 sh
  unsigned short* w1hb    = (unsigned short*)(ws + 262144);  // 262144 sh
  unsigned short* w1eb    = (unsigned short*)(ws + 393216);  // 262144 sh
  unsigned short* inputsb = (unsigned short*)(ws + 524288);  // 262144 sh

  // time-parallel precompute
  ar_fill<<<640, 256, 0, stream>>>(mels, ar);
  w2frag_fill<<<384, 256, 0, stream>>>(out_w2, w2frag);
  clear_hm<<<64, 256, 0, stream>>>((float*)hm);

  // prenet (fp32 VALU GEMM)
  gemm_nt<<<dim3(4, 32), 256, 0, stream>>>(ar, DD, prenet_w1, DD, p1, PP, DD, 1);
  gemm_nt<<<dim3(4, 32), 256, 0, stream>>>(p1, PP, prenet_w2, PP, p2, PP, PP, 1);

  // bf16 conversions (ar/p1 now dead -> overlay)
  f2b<<<512, 256, 0, stream>>>(w_ih,   w_ihb,   524288, 256, 256,  0);
  f2b<<<256, 256, 0, stream>>>(out_w1, w1hb,    262144, 512, 1024, 0);
  f2b<<<256, 256, 0, stream>>>(out_w1, w1eb,    262144, 512, 1024, 512);
  f2b<<<256, 256, 0, stream>>>(inputs, inputsb, 262144, 512, 512,  0);
  f2b<<<512, 256, 0, stream>>>(p2,     p2b,     524288, 256, 256,  0);

  // gates_x = p2 @ w_ih^T + b_ih + b_hh   M=2048 N=2048 K=256
  gemm_mfma<<<dim3(32, 32), 256, 0, stream>>>(p2b, 256, w_ihb, 256,
                                              b_ih, b_hh, gates_x, 2048, 256, 0);
  // zi = inputs @ W1_e^T + b1             M=512 N=512 K=512
  gemm_mfma<<<dim3(8, 8), 256, 0, stream>>>(inputsb, 512, w1eb, 512,
                                            out_b1, nullptr, zi, 512, 512, 0);

  // sequential LSTM (tagged words + two-phase acquire)
  lstm_seq<<<LB, LT, 0, stream>>>(w_hh, gates_x, h_allb, hm);

  // hv = h @ W1_h^T                       M=2048 N=512 K=512
  gemm_mfma<<<dim3(8, 32), 256, 0, stream>>>(h_allb, 512, w1hb, 512,
                                             nullptr, nullptr, hv, 512, 512, 0);

  // fused output net + emission (MFMA)
  outnet<<<2048, 256, 0, stream>>>(hv, zi, w2frag, out_b2, mels, inputs_len,
                                   em, lsn, lsp);

  // sequential HMM scan
  hmm_scan<<<1, 512, 0, stream>>>(em, lsn, lsp, inputs_len, mel_lens, (float*)d_out);
}

// Round 6
// 927.462 us; speedup vs baseline: 1.9445x; 1.6973x over previous
//
#include <hip/hip_runtime.h>
#include <math.h>

// Problem constants
#define T_STEPS 256
#define BB 8
#define NSTATE 64
#define DD 80
#define PP 256
#define HH 512
#define OO 512
#define NPARAM 161   // 2*D+1
#define PLS 171      // padded row stride for params in LDS (bank spread)
#define NEG_INF_F (-1000000.0f)

#define GSTR 88      // gemm_mfma LDS row stride in ushorts

typedef __attribute__((ext_vector_type(8))) short s16x8;
typedef __attribute__((ext_vector_type(4))) float f32x4;

union PairU { double d; float f[2]; unsigned u[2]; };

__device__ __forceinline__ float sigmoidf_(float x) { return 1.0f / (1.0f + __expf(-x)); }
__device__ __forceinline__ unsigned short bf16rne(float x) {
  union { float f; unsigned u; } v; v.f = x;
  unsigned r = (v.u + 0x7FFFu + ((v.u >> 16) & 1u)) >> 16;
  return (unsigned short)r;
}
__device__ __forceinline__ float bf2f(unsigned s) {
  union { unsigned u; float f; } v; v.u = s << 16; return v.f;
}

// ---------------------------------------------------------------------------
// prep kernels
// ---------------------------------------------------------------------------
__global__ void ar_fill(const float* __restrict__ mels, float* __restrict__ ar) {
  int idx = blockIdx.x * 256 + threadIdx.x;
  if (idx >= T_STEPS * BB * DD) return;
  int d = idx % DD; int r = idx / DD; int b = r % BB; int t = r / BB;
  ar[idx] = (t == 0) ? 0.0f : mels[(b * DD + d) * T_STEPS + (t - 1)];
}

// w2frag: B-fragment layout for mfma_f32_16x16x32_bf16 (verified in outnet)
__global__ void w2frag_fill(const float* __restrict__ w2, unsigned short* __restrict__ wf) {
  int idx = blockIdx.x * 256 + threadIdx.x;
  if (idx >= 16 * 12 * 64 * 8) return;
  int j = idx & 7, lane = (idx >> 3) & 63, nt = (idx >> 9) % 12, kb = idx / 6144;
  int p = nt * 16 + (lane & 15);
  int o = kb * 32 + ((lane >> 4) << 3) + j;
  float v = (p < NPARAM) ? w2[p * OO + o] : 0.0f;
  wf[idx] = bf16rne(v);
}

__global__ void clear_hm(float* __restrict__ p) {
  int i = blockIdx.x * 256 + threadIdx.x;
  if (i < 16384) p[i] = 0.0f;   // 64KB ring: 4 deep x 8 batches x 256 words
}

// fp32 -> bf16 conversion: dst[r*cols+c] = bf16(src[r*ld + off + c])
__global__ void f2b(const float* __restrict__ src, unsigned short* __restrict__ dst,
                    int total, int cols, int ld, int off) {
  int i = (blockIdx.x * 256 + threadIdx.x) * 4;
  if (i >= total) return;
  int r = i / cols, c = i % cols;
  float4 v = *(const float4*)&src[(size_t)r * ld + off + c];
  dst[i + 0] = bf16rne(v.x); dst[i + 1] = bf16rne(v.y);
  dst[i + 2] = bf16rne(v.z); dst[i + 3] = bf16rne(v.w);
}

// ---------------------------------------------------------------------------
// fp32 VALU GEMM (prenet only): C = relu(A @ B^T), handles K tails.
// ---------------------------------------------------------------------------
__global__ __launch_bounds__(256)
void gemm_nt(const float* __restrict__ A, int lda,
             const float* __restrict__ Bw, int ldb,
             float* __restrict__ C, int N, int K, int relu)
{
  __shared__ float As[32][64];
  __shared__ float Bs[32][64];
  const int tid = threadIdx.x;
  const int m0 = blockIdx.y * 64, n0 = blockIdx.x * 64;
  const int tm = tid & 15, tn = tid >> 4;
  float acc[4][4] = {{0.f,0.f,0.f,0.f},{0.f,0.f,0.f,0.f},{0.f,0.f,0.f,0.f},{0.f,0.f,0.f,0.f}};

  for (int k0 = 0; k0 < K; k0 += 32) {
#pragma unroll
    for (int half = 0; half < 2; ++half) {
      int mm = (tid >> 3) + half * 32;
      int kk = (tid & 7) * 4;
      const float* ap = &A[(size_t)(m0 + mm) * lda + k0 + kk];
      float4 av;
      if (k0 + kk + 3 < K) av = *(const float4*)ap;
      else {
        av.x = (k0 + kk + 0 < K) ? ap[0] : 0.f;
        av.y = (k0 + kk + 1 < K) ? ap[1] : 0.f;
        av.z = (k0 + kk + 2 < K) ? ap[2] : 0.f;
        av.w = (k0 + kk + 3 < K) ? ap[3] : 0.f;
      }
      As[kk + 0][mm] = av.x; As[kk + 1][mm] = av.y;
      As[kk + 2][mm] = av.z; As[kk + 3][mm] = av.w;
      const float* bp = &Bw[(size_t)(n0 + mm) * ldb + k0 + kk];
      float4 bv;
      if (k0 + kk + 3 < K) bv = *(const float4*)bp;
      else {
        bv.x = (k0 + kk + 0 < K) ? bp[0] : 0.f;
        bv.y = (k0 + kk + 1 < K) ? bp[1] : 0.f;
        bv.z = (k0 + kk + 2 < K) ? bp[2] : 0.f;
        bv.w = (k0 + kk + 3 < K) ? bp[3] : 0.f;
      }
      Bs[kk + 0][mm] = bv.x; Bs[kk + 1][mm] = bv.y;
      Bs[kk + 2][mm] = bv.z; Bs[kk + 3][mm] = bv.w;
    }
    __syncthreads();
#pragma unroll
    for (int kk = 0; kk < 32; ++kk) {
      float4 a4 = *(const float4*)&As[kk][tm * 4];
      float4 b4 = *(const float4*)&Bs[kk][tn * 4];
      float av[4] = {a4.x, a4.y, a4.z, a4.w};
      float bvv[4] = {b4.x, b4.y, b4.z, b4.w};
#pragma unroll
      for (int i = 0; i < 4; ++i)
#pragma unroll
        for (int j = 0; j < 4; ++j)
          acc[i][j] += av[i] * bvv[j];
    }
    __syncthreads();
  }
#pragma unroll
  for (int i = 0; i < 4; ++i) {
    int m = m0 + tm * 4 + i;
    float4 v;
    v.x = acc[i][0]; v.y = acc[i][1]; v.z = acc[i][2]; v.w = acc[i][3];
    if (relu) {
      v.x = fmaxf(v.x, 0.f); v.y = fmaxf(v.y, 0.f);
      v.z = fmaxf(v.z, 0.f); v.w = fmaxf(v.w, 0.f);
    }
    *(float4*)&C[(size_t)m * N + n0 + tn * 4] = v;
  }
}

// ---------------------------------------------------------------------------
// bf16 MFMA GEMM (fragment conventions verified by outnet)
// ---------------------------------------------------------------------------
__global__ __launch_bounds__(256)
void gemm_mfma(const unsigned short* __restrict__ A, int lda,
               const unsigned short* __restrict__ B, int ldb,
               const float* __restrict__ bias1, const float* __restrict__ bias2,
               float* __restrict__ C, int N, int K, int relu)
{
  __shared__ unsigned short As[64 * GSTR];
  __shared__ unsigned short Bs[64 * GSTR];
  const int tid = threadIdx.x;
  const int lane = tid & 63, wv = tid >> 6;
  const int m0 = blockIdx.y * 64, n0 = blockIdx.x * 64;
  const int srow = tid >> 3, scol = (tid & 7) * 8;

  f32x4 acc[4];
#pragma unroll
  for (int m = 0; m < 4; ++m) acc[m] = (f32x4){0.f, 0.f, 0.f, 0.f};

  for (int k0 = 0; k0 < K; k0 += 64) {
    __syncthreads();
    *(float4*)&As[srow * GSTR + scol] =
        *(const float4*)&A[(size_t)(m0 + srow) * lda + k0 + scol];
    *(float4*)&As[(srow + 32) * GSTR + scol] =
        *(const float4*)&A[(size_t)(m0 + srow + 32) * lda + k0 + scol];
    *(float4*)&Bs[srow * GSTR + scol] =
        *(const float4*)&B[(size_t)(n0 + srow) * ldb + k0 + scol];
    *(float4*)&Bs[(srow + 32) * GSTR + scol] =
        *(const float4*)&B[(size_t)(n0 + srow + 32) * ldb + k0 + scol];
    __syncthreads();
#pragma unroll
    for (int ks = 0; ks < 2; ++ks) {
      const int kk = ks * 32 + 8 * (lane >> 4);
      s16x8 bfr = *(const s16x8*)&Bs[(wv * 16 + (lane & 15)) * GSTR + kk];
#pragma unroll
      for (int m = 0; m < 4; ++m) {
        s16x8 afr = *(const s16x8*)&As[(m * 16 + (lane & 15)) * GSTR + kk];
        acc[m] = __builtin_amdgcn_mfma_f32_16x16x32_bf16(afr, bfr, acc[m], 0, 0, 0);
      }
    }
  }
  const int cn = n0 + wv * 16 + (lane & 15);
  float bj = 0.f;
  if (bias1) bj += bias1[cn];
  if (bias2) bj += bias2[cn];
  const int rbase = m0 + (lane >> 4) * 4;
#pragma unroll
  for (int m = 0; m < 4; ++m)
#pragma unroll
    for (int r = 0; r < 4; ++r) {
      float v = acc[m][r] + bj;
      if (relu) v = fmaxf(v, 0.f);
      C[(size_t)(rbase + m * 16 + r) * N + cn] = v;
    }
}

// ---------------------------------------------------------------------------
// persistent sequential LSTM v6: PER-BATCH sync groups (batches are
// independent!). 128 blocks = 8 batches x 16 j-slices (32 units each).
// Weights in VGPRs (64 packed-bf16 regs/thread); LDS ~4KB.
// Mailbox: per batch, 256 tagged words (2 bf16 h + tag, verified v4 format),
// ring depth 4, cleared per launch. Each thread spins on exactly ONE word.
// Fan-in per group: 16 blocks. Groups proceed independently.
// ---------------------------------------------------------------------------
__global__ __launch_bounds__(256)
void lstm_seq(const float* __restrict__ w_hh, const float* __restrict__ gates_x,
              unsigned short* __restrict__ h_allb, double* __restrict__ hm)
{
  __shared__ float hl[512];       // this batch's h[t-1], fp32
  __shared__ float red[2][128];   // k-half partial sums per row
  __shared__ float gl[128];       // gate pre-activations (rows g*32+jl)
  const int tid = threadIdx.x;
  const int b = blockIdx.x & 7;       // batch (group id)
  const int s = blockIdx.x >> 3;      // j-slice 0..15
  const int j0 = s * 32;
  const int row = tid & 127;          // 0..127 = g*32 + jl
  const int ks  = tid >> 7;           // k-half 0..1
  const int g = row >> 5, jl = row & 31;

  // weights -> VGPRs: w_hh[g*512 + j0 + jl][ks*256 .. +256), packed 2xbf16
  unsigned wreg[64];
  {
    const float* wr = &w_hh[((size_t)(g * HH + j0 + jl)) * HH + ks * 256];
#pragma unroll
    for (int c = 0; c < 64; ++c) {
      float2 wp = *(const float2*)&wr[c * 2];
      wreg[c] = (unsigned)bf16rne(wp.x) | ((unsigned)bf16rne(wp.y) << 16);
    }
  }
  float c_reg = 0.f;

  for (int t = 0; t < T_STEPS; ++t) {
    // prefetch gate-x for this row (overlaps the poll)
    float gx = 0.f;
    if (tid < 128)
      gx = gates_x[((size_t)t * BB + b) * (4 * HH) + (tid >> 5) * HH + j0 + (tid & 31)];

    // ---- acquire h[t-1]: each thread spins on ONE tagged word ----
    if (t == 0) {
      hl[2 * tid] = 0.f; hl[2 * tid + 1] = 0.f;
    } else {
      const double* ring = hm + ((size_t)((t - 1) & 3) * BB + b) * 256;
      PairU w;
      for (;;) {
        w.d = __hip_atomic_load(&ring[tid], __ATOMIC_RELAXED, __HIP_MEMORY_SCOPE_AGENT);
        if (w.u[1] == (unsigned)t) break;
        __builtin_amdgcn_s_sleep(1);
      }
      hl[2 * tid]     = bf2f(w.u[0] & 0xFFFFu);
      hl[2 * tid + 1] = bf2f(w.u[0] >> 16);
    }
    __syncthreads();

    // ---- matvec: this row, 256 k (broadcast hl reads, conflict-free) ----
    float acc = 0.f;
    const float* hk = &hl[ks * 256];
#pragma unroll
    for (int c = 0; c < 64; ++c) {
      float2 h2 = *(const float2*)&hk[c * 2];
      unsigned wp = wreg[c];
      union { unsigned u; float f; } lo, hi;
      lo.u = wp << 16; hi.u = wp & 0xFFFF0000u;
      acc += lo.f * h2.x + hi.f * h2.y;
    }
    red[ks][row] = acc;
    __syncthreads();

    // ---- k-half reduce + bias-x ----
    if (tid < 128) gl[tid] = red[0][tid] + red[1][tid] + gx;
    __syncthreads();

    // ---- c/h update + publish (tag rides with data) ----
    if (tid < 32) {
      float iv = gl[tid], fv = gl[32 + tid], gv = gl[64 + tid], ov = gl[96 + tid];
      float ct = sigmoidf_(fv) * c_reg + sigmoidf_(iv) * tanhf(gv);
      c_reg = ct;
      float h = sigmoidf_(ov) * tanhf(ct);
      unsigned short hb = bf16rne(h);
      h_allb[((size_t)t * BB + b) * HH + j0 + tid] = hb;
      float hp = __shfl_xor(h, 1);   // partner unit jl^1
      if ((tid & 1) == 0) {
        PairU pv;
        pv.u[0] = (unsigned)hb | ((unsigned)bf16rne(hp) << 16);
        pv.u[1] = (unsigned)(t + 1);
        __hip_atomic_store(&hm[((size_t)(t & 3) * BB + b) * 256 + s * 16 + (tid >> 1)],
                           pv.d, __ATOMIC_RELAXED, __HIP_MEMORY_SCOPE_AGENT);
      }
    }
    // no trailing barrier needed: next-iter LDS writes are fenced by the
    // two barriers above (see hazard analysis in journal).
  }
}

// ---------------------------------------------------------------------------
// fused output net + emission, MFMA (verified layout). Block per (t,b).
// ---------------------------------------------------------------------------
__global__ __launch_bounds__(256)
void outnet(const float* __restrict__ hv, const float* __restrict__ zi,
            const unsigned short* __restrict__ w2frag, const float* __restrict__ b2,
            const float* __restrict__ mels, const int* __restrict__ inputs_len,
            float* __restrict__ em_out, float* __restrict__ lsn_out,
            float* __restrict__ lsp_out)
{
  __shared__ float hvs[OO];
  __shared__ float xts[96];
  __shared__ s16x8 Afr[2][256];
  __shared__ float pl[64 * PLS];
  const int tid = threadIdx.x;
  const int tb = blockIdx.x;
  const int t = tb >> 3, b = tb & 7;
  const int lane = tid & 63, wv = tid >> 6;

  if (tid < 128) *(float4*)&hvs[tid * 4] = *(const float4*)&hv[(size_t)tb * OO + tid * 4];
  if (tid < DD) xts[tid] = mels[(b * DD + tid) * T_STEPS + t];
  __syncthreads();

  const int n_state = wv * 16 + (lane & 15);
  const int osub = (lane >> 4) * 8;
  const float* zbase = zi + (size_t)(b * 64 + n_state) * OO;

  auto genA = [&](int kb, int buf) {
    int ob = kb * 32 + osub;
    float4 z0 = *(const float4*)&zbase[ob];
    float4 z1 = *(const float4*)&zbase[ob + 4];
    float4 h0 = *(const float4*)&hvs[ob];
    float4 h1 = *(const float4*)&hvs[ob + 4];
    s16x8 s;
    s[0] = bf16rne(fmaxf(z0.x + h0.x, 0.f));
    s[1] = bf16rne(fmaxf(z0.y + h0.y, 0.f));
    s[2] = bf16rne(fmaxf(z0.z + h0.z, 0.f));
    s[3] = bf16rne(fmaxf(z0.w + h0.w, 0.f));
    s[4] = bf16rne(fmaxf(z1.x + h1.x, 0.f));
    s[5] = bf16rne(fmaxf(z1.y + h1.y, 0.f));
    s[6] = bf16rne(fmaxf(z1.z + h1.z, 0.f));
    s[7] = bf16rne(fmaxf(z1.w + h1.w, 0.f));
    Afr[buf][tid] = s;
  };
  genA(0, 0);

  f32x4 acc[4][3];
#pragma unroll
  for (int m = 0; m < 4; ++m)
#pragma unroll
    for (int n = 0; n < 3; ++n) acc[m][n] = (f32x4){0.f, 0.f, 0.f, 0.f};

  const unsigned short* bfp = w2frag + ((size_t)(wv * 3) * 64 + lane) * 8;

  for (int kb = 0; kb < 16; ++kb) {
    __syncthreads();
    s16x8 bf[3];
#pragma unroll
    for (int ntl = 0; ntl < 3; ++ntl)
      bf[ntl] = *(const s16x8*)&bfp[(size_t)kb * 6144 + ntl * 512];
    if (kb < 15) genA(kb + 1, (kb + 1) & 1);
    s16x8 af[4];
#pragma unroll
    for (int m = 0; m < 4; ++m) af[m] = Afr[kb & 1][m * 64 + lane];
#pragma unroll
    for (int m = 0; m < 4; ++m)
#pragma unroll
      for (int ntl = 0; ntl < 3; ++ntl)
        acc[m][ntl] = __builtin_amdgcn_mfma_f32_16x16x32_bf16(af[m], bf[ntl], acc[m][ntl], 0, 0, 0);
  }

  const int prow4 = (lane >> 4) * 4;
#pragma unroll
  for (int ntl = 0; ntl < 3; ++ntl) {
    int p = (wv * 3 + ntl) * 16 + (lane & 15);
    if (p < NPARAM) {
      float bb2 = b2[p];
#pragma unroll
      for (int m = 0; m < 4; ++m)
#pragma unroll
        for (int r = 0; r < 4; ++r)
          pl[(m * 16 + prow4 + r) * PLS + p] = acc[m][ntl][r] + bb2;
    }
  }
  __syncthreads();

  const int ne = tid >> 2, dq = tid & 3;
  float s = 0.f;
  for (int d = dq * 20; d < dq * 20 + 20; ++d) {
    float mean = pl[ne * PLS + d];
    float sp   = pl[ne * PLS + 80 + d];
    float x = xts[d];
    float sf = (sp > 20.f) ? sp : log1pf(__expf(sp));
    float sd = fmaxf(sf, 0.001f);
    float zz = (x - mean) / sd;
    s += -0.5f * zz * zz - __logf(sd) - 0.91893853320467274f;
  }
  s += __shfl_xor(s, 1);
  s += __shfl_xor(s, 2);
  if (dq == 0) {
    int ilen = inputs_len[b];
    em_out[(size_t)tb * NSTATE + ne] = (ne < ilen) ? s : 0.f;
    float tv = pl[ne * PLS + 160];
    lsp_out[(size_t)tb * NSTATE + ne] = __logf(fmaxf(sigmoidf_(tv), 1e-4f));
    lsn_out[(size_t)tb * NSTATE + ne] = __logf(fmaxf(sigmoidf_(-tv), 1e-4f));
  }
}

// ---------------------------------------------------------------------------
// sequential HMM forward scan: 1 block, wave per batch, t+1 load prefetch.
// ---------------------------------------------------------------------------
__global__ __launch_bounds__(512)
void hmm_scan(const float* __restrict__ em, const float* __restrict__ lsn,
              const float* __restrict__ lsp, const int* __restrict__ inputs_len,
              const int* __restrict__ mel_lens, float* __restrict__ out)
{
  const int tid = threadIdx.x;
  const int b = tid >> 6, n = tid & 63;
  const int ilen = inputs_len[b], mlen = mel_lens[b];
  const bool mask = n < ilen;
  const size_t stepo = (size_t)BB * NSTATE;
  const size_t base = (size_t)b * NSTATE + n;
  float alpha = 0.f, slc = 0.f, la = NEG_INF_F, llsp = 0.f;
  float e = em[base], ln_ = lsn[base], lp_ = lsp[base];

  for (int t = 0; t < T_STEPS; ++t) {
    float en = 0.f, lnn = 0.f, lpn = 0.f;
    if (t + 1 < T_STEPS) {
      size_t nb = base + (size_t)(t + 1) * stepo;
      en = em[nb]; lnn = lsn[nb]; lpn = lsp[nb];
    }
    float at;
    if (t == 0) {
      at = ((n == 0) ? 0.f : NEG_INF_F) + e;
    } else {
      float stay = alpha + ln_;
      float lvs = alpha + lp_;
      float lv = __shfl_up(lvs, 1, 64);
      if (n == 0) lv = NEG_INF_F;
      float mx = fmaxf(stay, lv), mn = fminf(stay, lv);
      float tt = mask ? (mx + log1pf(__expf(mn - mx))) : NEG_INF_F;
      at = e + tt;
    }
    float m = at;
#pragma unroll
    for (int off = 1; off < 64; off <<= 1) m = fmaxf(m, __shfl_xor(m, off));
    float es = __expf(at - m);
#pragma unroll
    for (int off = 1; off < 64; off <<= 1) es += __shfl_xor(es, off);
    float logc = m + __logf(es);
    alpha = at - logc;
    if (t < mlen) slc += logc;
    if (t == mlen - 1) { la = mask ? alpha : NEG_INF_F; llsp = lp_; }
    e = en; ln_ = lnn; lp_ = lpn;
  }

  float v = la + ((n == ilen - 1) ? llsp : NEG_INF_F);
  float m = v;
#pragma unroll
  for (int off = 1; off < 64; off <<= 1) m = fmaxf(m, __shfl_xor(m, off));
  float es = __expf(v - m);
#pragma unroll
  for (int off = 1; off < 64; off <<= 1) es += __shfl_xor(es, off);
  float sfin = m + __logf(es);
  if (n == 0) out[b] = slc + sfin;
}

// ---------------------------------------------------------------------------
extern "C" void kernel_launch(void* const* d_in, const int* in_sizes, int n_in,
                              void* d_out, int out_size, void* d_ws, size_t ws_size,
                              hipStream_t stream)
{
  const float* inputs    = (const float*)d_in[0];
  const float* mels      = (const float*)d_in[1];
  const float* prenet_w1 = (const float*)d_in[2];
  const float* prenet_w2 = (const float*)d_in[3];
  const float* w_ih      = (const float*)d_in[4];
  const float* w_hh      = (const float*)d_in[5];
  const float* b_ih      = (const float*)d_in[6];
  const float* b_hh      = (const float*)d_in[7];
  const float* out_w1    = (const float*)d_in[8];
  const float* out_b1    = (const float*)d_in[9];
  const float* out_w2    = (const float*)d_in[10];
  const float* out_b2    = (const float*)d_in[11];
  const int* inputs_len  = (const int*)d_in[12];
  const int* mel_lens    = (const int*)d_in[13];

  float* ws = (float*)d_ws;
  float* ar      = ws;                        // 163840
  float* p1      = ws + 163840;               // 524288
  float* p2      = ws + 688128;               // 524288
  float* gates_x = ws + 1212416;              // 4194304
  float* zi      = ws + 5406720;              // 262144  ([b*64+n][o])
  unsigned short* w2frag = (unsigned short*)(ws + 5668864);  // 98304 sh
  float* hv      = ws + 5718016;              // 1048576
  float* em      = ws + 6766592;              // 131072
  float* lsn     = ws + 6897664;              // 131072
  float* lsp     = ws + 7028736;              // 131072
  double* hm     = (double*)(ws + 7159808);   // 8192 doubles (64KB ring)
  unsigned short* p2b    = (unsigned short*)(ws + 7176192);  // 524288 sh
  unsigned short* h_allb = (unsigned short*)(ws + 7438336);  // 1048576 sh
  // overlay (valid after prenet):
  unsigned short* w_ihb   = (unsigned short*)(ws + 0);       // 524288 sh
  unsigned short* w1hb    = (unsigned short*)(ws + 262144);  // 262144 sh
  unsigned short* w1eb    = (unsigned short*)(ws + 393216);  // 262144 sh
  unsigned short* inputsb = (unsigned short*)(ws + 524288);  // 262144 sh

  // time-parallel precompute
  ar_fill<<<640, 256, 0, stream>>>(mels, ar);
  w2frag_fill<<<384, 256, 0, stream>>>(out_w2, w2frag);
  clear_hm<<<64, 256, 0, stream>>>((float*)hm);

  // prenet (fp32 VALU GEMM)
  gemm_nt<<<dim3(4, 32), 256, 0, stream>>>(ar, DD, prenet_w1, DD, p1, PP, DD, 1);
  gemm_nt<<<dim3(4, 32), 256, 0, stream>>>(p1, PP, prenet_w2, PP, p2, PP, PP, 1);

  // bf16 conversions (ar/p1 now dead -> overlay)
  f2b<<<512, 256, 0, stream>>>(w_ih,   w_ihb,   524288, 256, 256,  0);
  f2b<<<256, 256, 0, stream>>>(out_w1, w1hb,    262144, 512, 1024, 0);
  f2b<<<256, 256, 0, stream>>>(out_w1, w1eb,    262144, 512, 1024, 512);
  f2b<<<256, 256, 0, stream>>>(inputs, inputsb, 262144, 512, 512,  0);
  f2b<<<512, 256, 0, stream>>>(p2,     p2b,     524288, 256, 256,  0);

  // gates_x = p2 @ w_ih^T + b_ih + b_hh   M=2048 N=2048 K=256
  gemm_mfma<<<dim3(32, 32), 256, 0, stream>>>(p2b, 256, w_ihb, 256,
                                              b_ih, b_hh, gates_x, 2048, 256, 0);
  // zi = inputs @ W1_e^T + b1             M=512 N=512 K=512
  gemm_mfma<<<dim3(8, 8), 256, 0, stream>>>(inputsb, 512, w1eb, 512,
                                            out_b1, nullptr, zi, 512, 512, 0);

  // sequential LSTM (per-batch sync groups, weights in VGPRs)
  lstm_seq<<<128, 256, 0, stream>>>(w_hh, gates_x, h_allb, hm);

  // hv = h @ W1_h^T                       M=2048 N=512 K=512
  gemm_mfma<<<dim3(8, 32), 256, 0, stream>>>(h_allb, 512, w1hb, 512,
                                             nullptr, nullptr, hv, 512, 512, 0);

  // fused output net + emission (MFMA)
  outnet<<<2048, 256, 0, stream>>>(hv, zi, w2frag, out_b2, mels, inputs_len,
                                   em, lsn, lsp);

  // sequential HMM scan
  hmm_scan<<<1, 512, 0, stream>>>(em, lsn, lsp, inputs_len, mel_lens, (float*)d_out);
}

// Round 7
// 798.457 us; speedup vs baseline: 2.2587x; 1.1616x over previous
//
#include <hip/hip_runtime.h>
#include <math.h>

// Problem constants
#define T_STEPS 256
#define BB 8
#define NSTATE 64
#define DD 80
#define PP 256
#define HH 512
#define OO 512
#define NPARAM 161   // 2*D+1
#define PLS 171      // padded row stride for params in LDS (bank spread)
#define NEG_INF_F (-1000000.0f)

#define GSTR 88      // gemm_mfma LDS row stride in ushorts

typedef __attribute__((ext_vector_type(8))) short s16x8;
typedef __attribute__((ext_vector_type(4))) float f32x4;
typedef _Float16 h2t __attribute__((ext_vector_type(2)));

union PairU { double d; float f[2]; unsigned u[2]; };

__device__ __forceinline__ float sigmoidf_(float x) { return 1.0f / (1.0f + __expf(-x)); }
__device__ __forceinline__ unsigned short bf16rne(float x) {
  union { float f; unsigned u; } v; v.f = x;
  unsigned r = (v.u + 0x7FFFu + ((v.u >> 16) & 1u)) >> 16;
  return (unsigned short)r;
}
__device__ __forceinline__ float bf2f(unsigned s) {
  union { unsigned u; float f; } v; v.u = s << 16; return v.f;
}
__device__ __forceinline__ float fdot2_(unsigned a, unsigned b, float c) {
  union { unsigned u; h2t h; } ua, ub; ua.u = a; ub.u = b;
  return __builtin_amdgcn_fdot2(ua.h, ub.h, c, false);
}
__device__ __forceinline__ unsigned packf16(float a, float b) {
  union { unsigned u; _Float16 f[2]; } p;
  p.f[0] = (_Float16)a; p.f[1] = (_Float16)b;
  return p.u;
}

// ---------------------------------------------------------------------------
// fused conversion/prep kernel: all weight reformatting + mailbox clear.
// Segments over a grand linear index (items):
//  s0 w_ihb   [0,524288)        bf16 linear of w_ih [2048][256]
//  s1 w1hb    [524288,786432)   bf16 of out_w1[:, 0:512]
//  s2 w1eb    [786432,1048576)  bf16 of out_w1[:, 512:1024]
//  s3 inputsb [1048576,1310720) bf16 linear of inputs
//  s4 w2b     [1310720,1376256) bf16 linear of prenet_w2 [256][256]
//  s5 w1b     [1376256,1409024) bf16 [256][128] zero-padded K of prenet_w1
//  s6 w2frag  [1409024,1507328) MFMA B-fragments of out_w2 (verified layout)
//  s7 whh16   [1507328,2031616) fp16-pair pack of w_hh rows (uint writes)
//  s8 hm      [2031616,2048000) mailbox ring clear (float writes)
// ---------------------------------------------------------------------------
__global__ __launch_bounds__(256)
void conv_all(const float* __restrict__ w_ih, const float* __restrict__ out_w1,
              const float* __restrict__ inputs, const float* __restrict__ pw2,
              const float* __restrict__ pw1, const float* __restrict__ w2,
              const float* __restrict__ w_hh,
              unsigned short* __restrict__ w_ihb, unsigned short* __restrict__ w1hb,
              unsigned short* __restrict__ w1eb, unsigned short* __restrict__ inputsb,
              unsigned short* __restrict__ w2b, unsigned short* __restrict__ w1b,
              unsigned short* __restrict__ w2frag, unsigned* __restrict__ whh16,
              float* __restrict__ hmf)
{
  int idx = blockIdx.x * 256 + threadIdx.x;
  if (idx < 524288) {
    w_ihb[idx] = bf16rne(w_ih[idx]);
  } else if (idx < 786432) {
    int i = idx - 524288; int r = i >> 9, c = i & 511;
    w1hb[i] = bf16rne(out_w1[(size_t)r * 1024 + c]);
  } else if (idx < 1048576) {
    int i = idx - 786432; int r = i >> 9, c = i & 511;
    w1eb[i] = bf16rne(out_w1[(size_t)r * 1024 + 512 + c]);
  } else if (idx < 1310720) {
    int i = idx - 1048576;
    inputsb[i] = bf16rne(inputs[i]);
  } else if (idx < 1376256) {
    int i = idx - 1310720;
    w2b[i] = bf16rne(pw2[i]);
  } else if (idx < 1409024) {
    int i = idx - 1376256; int r = i >> 7, c = i & 127;
    w1b[i] = (c < DD) ? bf16rne(pw1[r * DD + c]) : (unsigned short)0;
  } else if (idx < 1507328) {
    int i = idx - 1409024;
    int j = i & 7, lane = (i >> 3) & 63, nt = (i >> 9) % 12, kb = i / 6144;
    int p = nt * 16 + (lane & 15);
    int o = kb * 32 + ((lane >> 4) << 3) + j;
    float v = (p < NPARAM) ? w2[p * OO + o] : 0.0f;
    w2frag[i] = bf16rne(v);
  } else if (idx < 2031616) {
    int i = idx - 1507328;                 // uint index: row*256 + pair
    int gr = i >> 8, pp = i & 255;
    const float* src = &w_hh[(size_t)gr * HH + pp * 2];
    whh16[i] = packf16(src[0], src[1]);
  } else if (idx < 2048000) {
    hmf[idx - 2031616] = 0.0f;
  }
}

// arb: bf16 zero-K-padded autoregressive input [2048][128]
__global__ void arb_fill(const float* __restrict__ mels, unsigned short* __restrict__ arb) {
  int idx = blockIdx.x * 256 + threadIdx.x;
  if (idx >= 2048 * 128) return;
  int c = idx & 127; int r = idx >> 7; int b = r & 7; int t = r >> 3;
  float v = (t == 0 || c >= DD) ? 0.0f : mels[(b * DD + c) * T_STEPS + (t - 1)];
  arb[idx] = bf16rne(v);
}

// ---------------------------------------------------------------------------
// bf16 MFMA GEMM (fragment conventions verified by outnet).
// obf=1: emit bf16 (ushort) C; else fp32.
// ---------------------------------------------------------------------------
__global__ __launch_bounds__(256)
void gemm_mfma(const unsigned short* __restrict__ A, int lda,
               const unsigned short* __restrict__ B, int ldb,
               const float* __restrict__ bias1, const float* __restrict__ bias2,
               void* __restrict__ Cout, int N, int K, int relu, int obf)
{
  __shared__ unsigned short As[64 * GSTR];
  __shared__ unsigned short Bs[64 * GSTR];
  const int tid = threadIdx.x;
  const int lane = tid & 63, wv = tid >> 6;
  const int m0 = blockIdx.y * 64, n0 = blockIdx.x * 64;
  const int srow = tid >> 3, scol = (tid & 7) * 8;

  f32x4 acc[4];
#pragma unroll
  for (int m = 0; m < 4; ++m) acc[m] = (f32x4){0.f, 0.f, 0.f, 0.f};

  for (int k0 = 0; k0 < K; k0 += 64) {
    __syncthreads();
    *(float4*)&As[srow * GSTR + scol] =
        *(const float4*)&A[(size_t)(m0 + srow) * lda + k0 + scol];
    *(float4*)&As[(srow + 32) * GSTR + scol] =
        *(const float4*)&A[(size_t)(m0 + srow + 32) * lda + k0 + scol];
    *(float4*)&Bs[srow * GSTR + scol] =
        *(const float4*)&B[(size_t)(n0 + srow) * ldb + k0 + scol];
    *(float4*)&Bs[(srow + 32) * GSTR + scol] =
        *(const float4*)&B[(size_t)(n0 + srow + 32) * ldb + k0 + scol];
    __syncthreads();
#pragma unroll
    for (int ks = 0; ks < 2; ++ks) {
      const int kk = ks * 32 + 8 * (lane >> 4);
      s16x8 bfr = *(const s16x8*)&Bs[(wv * 16 + (lane & 15)) * GSTR + kk];
#pragma unroll
      for (int m = 0; m < 4; ++m) {
        s16x8 afr = *(const s16x8*)&As[(m * 16 + (lane & 15)) * GSTR + kk];
        acc[m] = __builtin_amdgcn_mfma_f32_16x16x32_bf16(afr, bfr, acc[m], 0, 0, 0);
      }
    }
  }
  const int cn = n0 + wv * 16 + (lane & 15);
  float bj = 0.f;
  if (bias1) bj += bias1[cn];
  if (bias2) bj += bias2[cn];
  const int rbase = m0 + (lane >> 4) * 4;
#pragma unroll
  for (int m = 0; m < 4; ++m)
#pragma unroll
    for (int r = 0; r < 4; ++r) {
      float v = acc[m][r] + bj;
      if (relu) v = fmaxf(v, 0.f);
      size_t ci = (size_t)(rbase + m * 16 + r) * N + cn;
      if (obf) ((unsigned short*)Cout)[ci] = bf16rne(v);
      else     ((float*)Cout)[ci] = v;
    }
}

// ---------------------------------------------------------------------------
// persistent sequential LSTM v7: per-batch groups (8 x 16 blocks), two-phase
// acquire (16 lanes spin on per-producer word-0; bulk tag-verified load once),
// fp16-pair weights in VGPRs + v_dot2_f32_f16 matvec (full k coverage —
// fixes v6's half-k bug), fp16-pair mailbox payload.
// ---------------------------------------------------------------------------
__global__ __launch_bounds__(256)
void lstm_seq(const unsigned* __restrict__ whh16, const unsigned short* __restrict__ gatesb,
              unsigned short* __restrict__ h_allb, double* __restrict__ hm)
{
  __shared__ unsigned hl16[256];   // h[t-1] as 256 fp16-pairs
  __shared__ float red[2][128];
  __shared__ float gl[128];
  const int tid = threadIdx.x;
  const int b = blockIdx.x & 7;       // batch group
  const int s = blockIdx.x >> 3;      // j-slice 0..15 (32 units)
  const int j0 = s * 32;
  const int row = tid & 127;          // g*32+jl
  const int ks  = tid >> 7;           // k-half
  const int g = row >> 5, jl = row & 31;
  const int gr = g * HH + j0 + jl;    // global gate-row

  // weights -> VGPRs: 128 fp16-pairs = 256 k elems (this thread's k-half)
  unsigned wreg[128];
  {
    const unsigned* wp = &whh16[(size_t)gr * 256 + ks * 128];
#pragma unroll
    for (int c = 0; c < 128; ++c) wreg[c] = wp[c];
  }
  float c_reg = 0.f;

  for (int t = 0; t < T_STEPS; ++t) {
    // prefetch this row's gate-x (bf16), independent of the poll
    float gx = 0.f;
    if (tid < 128)
      gx = bf2f(gatesb[((size_t)t * BB + b) * 2048 + gr]);

    // ---- acquire h[t-1] ----
    if (t == 0) {
      hl16[tid] = 0u;
      __syncthreads();
    } else {
      const double* ring = hm + ((size_t)((t - 1) & 3) * BB + b) * 256;
      // phase 1: 16 lanes spin, one per producer (word-0 of its 128B line)
      if (tid < 16) {
        for (;;) {
          PairU w;
          w.d = __hip_atomic_load(&ring[tid * 16], __ATOMIC_RELAXED, __HIP_MEMORY_SCOPE_AGENT);
          if (__all(w.u[1] == (unsigned)t)) break;
          __builtin_amdgcn_s_sleep(1);
        }
      }
      __syncthreads();
      // phase 2: bulk load once, tag-verified (stragglers ~0: producer's 16
      // words = one line, stored by one wave-instruction)
      PairU w;
      for (;;) {
        w.d = __hip_atomic_load(&ring[tid], __ATOMIC_RELAXED, __HIP_MEMORY_SCOPE_AGENT);
        if (w.u[1] == (unsigned)t) break;
        __builtin_amdgcn_s_sleep(1);
      }
      hl16[tid] = w.u[0];
      __syncthreads();
    }

    // ---- matvec: row x 256 k via fdot2, 4 independent chains ----
    float a0 = 0.f, a1 = 0.f, a2 = 0.f, a3 = 0.f;
    const unsigned* hp = &hl16[ks * 128];
#pragma unroll
    for (int c = 0; c < 128; c += 4) {
      a0 = fdot2_(wreg[c + 0], hp[c + 0], a0);
      a1 = fdot2_(wreg[c + 1], hp[c + 1], a1);
      a2 = fdot2_(wreg[c + 2], hp[c + 2], a2);
      a3 = fdot2_(wreg[c + 3], hp[c + 3], a3);
    }
    red[ks][row] = (a0 + a1) + (a2 + a3);
    __syncthreads();

    if (tid < 128) gl[tid] = red[0][tid] + red[1][tid] + gx;
    __syncthreads();

    // ---- c/h update + publish (mailbox store first) ----
    if (tid < 32) {
      float iv = gl[tid], fv = gl[32 + tid], gv = gl[64 + tid], ov = gl[96 + tid];
      float ct = sigmoidf_(fv) * c_reg + sigmoidf_(iv) * tanhf(gv);
      c_reg = ct;
      float h = sigmoidf_(ov) * tanhf(ct);
      float hpart = __shfl_xor(h, 1);   // partner unit jl^1
      if ((tid & 1) == 0) {
        PairU pv;
        pv.u[0] = packf16(h, hpart);
        pv.u[1] = (unsigned)(t + 1);
        __hip_atomic_store(&hm[((size_t)(t & 3) * BB + b) * 256 + s * 16 + (tid >> 1)],
                           pv.d, __ATOMIC_RELAXED, __HIP_MEMORY_SCOPE_AGENT);
      }
      h_allb[((size_t)t * BB + b) * HH + j0 + tid] = bf16rne(h);
    }
    // no trailing barrier: next-iter LDS writes are fenced by the phase
    // barriers (all threads must pass this step's gl barrier first).
  }
}

// ---------------------------------------------------------------------------
// fused output net + emission, MFMA (verified layout). Block per (t,b).
// Emissions packed into elp float4 {em, lsn, lsp, 0}.
// ---------------------------------------------------------------------------
__global__ __launch_bounds__(256)
void outnet(const float* __restrict__ hv, const float* __restrict__ zi,
            const unsigned short* __restrict__ w2frag, const float* __restrict__ b2,
            const float* __restrict__ mels, const int* __restrict__ inputs_len,
            float* __restrict__ elp)
{
  __shared__ float hvs[OO];
  __shared__ float xts[96];
  __shared__ s16x8 Afr[2][256];
  __shared__ float pl[64 * PLS];
  const int tid = threadIdx.x;
  const int tb = blockIdx.x;
  const int t = tb >> 3, b = tb & 7;
  const int lane = tid & 63, wv = tid >> 6;

  if (tid < 128) *(float4*)&hvs[tid * 4] = *(const float4*)&hv[(size_t)tb * OO + tid * 4];
  if (tid < DD) xts[tid] = mels[(b * DD + tid) * T_STEPS + t];
  __syncthreads();

  const int n_state = wv * 16 + (lane & 15);
  const int osub = (lane >> 4) * 8;
  const float* zbase = zi + (size_t)(b * 64 + n_state) * OO;

  auto genA = [&](int kb, int buf) {
    int ob = kb * 32 + osub;
    float4 z0 = *(const float4*)&zbase[ob];
    float4 z1 = *(const float4*)&zbase[ob + 4];
    float4 h0 = *(const float4*)&hvs[ob];
    float4 h1 = *(const float4*)&hvs[ob + 4];
    s16x8 s;
    s[0] = bf16rne(fmaxf(z0.x + h0.x, 0.f));
    s[1] = bf16rne(fmaxf(z0.y + h0.y, 0.f));
    s[2] = bf16rne(fmaxf(z0.z + h0.z, 0.f));
    s[3] = bf16rne(fmaxf(z0.w + h0.w, 0.f));
    s[4] = bf16rne(fmaxf(z1.x + h1.x, 0.f));
    s[5] = bf16rne(fmaxf(z1.y + h1.y, 0.f));
    s[6] = bf16rne(fmaxf(z1.z + h1.z, 0.f));
    s[7] = bf16rne(fmaxf(z1.w + h1.w, 0.f));
    Afr[buf][tid] = s;
  };
  genA(0, 0);

  f32x4 acc[4][3];
#pragma unroll
  for (int m = 0; m < 4; ++m)
#pragma unroll
    for (int n = 0; n < 3; ++n) acc[m][n] = (f32x4){0.f, 0.f, 0.f, 0.f};

  const unsigned short* bfp = w2frag + ((size_t)(wv * 3) * 64 + lane) * 8;

  for (int kb = 0; kb < 16; ++kb) {
    __syncthreads();
    s16x8 bf[3];
#pragma unroll
    for (int ntl = 0; ntl < 3; ++ntl)
      bf[ntl] = *(const s16x8*)&bfp[(size_t)kb * 6144 + ntl * 512];
    if (kb < 15) genA(kb + 1, (kb + 1) & 1);
    s16x8 af[4];
#pragma unroll
    for (int m = 0; m < 4; ++m) af[m] = Afr[kb & 1][m * 64 + lane];
#pragma unroll
    for (int m = 0; m < 4; ++m)
#pragma unroll
      for (int ntl = 0; ntl < 3; ++ntl)
        acc[m][ntl] = __builtin_amdgcn_mfma_f32_16x16x32_bf16(af[m], bf[ntl], acc[m][ntl], 0, 0, 0);
  }

  const int prow4 = (lane >> 4) * 4;
#pragma unroll
  for (int ntl = 0; ntl < 3; ++ntl) {
    int p = (wv * 3 + ntl) * 16 + (lane & 15);
    if (p < NPARAM) {
      float bb2 = b2[p];
#pragma unroll
      for (int m = 0; m < 4; ++m)
#pragma unroll
        for (int r = 0; r < 4; ++r)
          pl[(m * 16 + prow4 + r) * PLS + p] = acc[m][ntl][r] + bb2;
    }
  }
  __syncthreads();

  const int ne = tid >> 2, dq = tid & 3;
  float s = 0.f;
  for (int d = dq * 20; d < dq * 20 + 20; ++d) {
    float mean = pl[ne * PLS + d];
    float sp   = pl[ne * PLS + 80 + d];
    float x = xts[d];
    float sf = (sp > 20.f) ? sp : log1pf(__expf(sp));
    float sd = fmaxf(sf, 0.001f);
    float zz = (x - mean) / sd;
    s += -0.5f * zz * zz - __logf(sd) - 0.91893853320467274f;
  }
  s += __shfl_xor(s, 1);
  s += __shfl_xor(s, 2);
  if (dq == 0) {
    int ilen = inputs_len[b];
    float tv = pl[ne * PLS + 160];
    float4 o;
    o.x = (ne < ilen) ? s : 0.f;                       // emission (masked)
    o.y = __logf(fmaxf(sigmoidf_(-tv), 1e-4f));        // log sig(-tv)
    o.z = __logf(fmaxf(sigmoidf_(tv), 1e-4f));         // log sig(tv)
    o.w = 0.f;
    *(float4*)&elp[((size_t)tb * NSTATE + ne) * 4] = o;
  }
}

// ---------------------------------------------------------------------------
// sequential HMM forward scan: 1 block, wave per batch, float4 loads + prefetch.
// ---------------------------------------------------------------------------
__global__ __launch_bounds__(512)
void hmm_scan(const float* __restrict__ elp, const int* __restrict__ inputs_len,
              const int* __restrict__ mel_lens, float* __restrict__ out)
{
  const int tid = threadIdx.x;
  const int b = tid >> 6, n = tid & 63;
  const int ilen = inputs_len[b], mlen = mel_lens[b];
  const bool mask = n < ilen;
  const float4* e4 = (const float4*)elp;
  const size_t base = (size_t)b * NSTATE + n;
  float alpha = 0.f, slc = 0.f, la = NEG_INF_F, llsp = 0.f;
  float4 cur = e4[base];

  for (int t = 0; t < T_STEPS; ++t) {
    float4 nxt = {0.f, 0.f, 0.f, 0.f};
    if (t + 1 < T_STEPS) nxt = e4[base + (size_t)(t + 1) * BB * NSTATE];
    float e = cur.x, ln_ = cur.y, lp_ = cur.z;
    float at;
    if (t == 0) {
      at = ((n == 0) ? 0.f : NEG_INF_F) + e;
    } else {
      float stay = alpha + ln_;
      float lvs = alpha + lp_;
      float lv = __shfl_up(lvs, 1, 64);
      if (n == 0) lv = NEG_INF_F;
      float mx = fmaxf(stay, lv), mn = fminf(stay, lv);
      float tt = mask ? (mx + log1pf(__expf(mn - mx))) : NEG_INF_F;
      at = e + tt;
    }
    float m = at;
#pragma unroll
    for (int off = 1; off < 64; off <<= 1) m = fmaxf(m, __shfl_xor(m, off));
    float es = __expf(at - m);
#pragma unroll
    for (int off = 1; off < 64; off <<= 1) es += __shfl_xor(es, off);
    float logc = m + __logf(es);
    alpha = at - logc;
    if (t < mlen) slc += logc;
    if (t == mlen - 1) { la = mask ? alpha : NEG_INF_F; llsp = lp_; }
    cur = nxt;
  }

  float v = la + ((n == ilen - 1) ? llsp : NEG_INF_F);
  float m = v;
#pragma unroll
  for (int off = 1; off < 64; off <<= 1) m = fmaxf(m, __shfl_xor(m, off));
  float es = __expf(v - m);
#pragma unroll
  for (int off = 1; off < 64; off <<= 1) es += __shfl_xor(es, off);
  float sfin = m + __logf(es);
  if (n == 0) out[b] = slc + sfin;
}

// ---------------------------------------------------------------------------
extern "C" void kernel_launch(void* const* d_in, const int* in_sizes, int n_in,
                              void* d_out, int out_size, void* d_ws, size_t ws_size,
                              hipStream_t stream)
{
  const float* inputs    = (const float*)d_in[0];
  const float* mels      = (const float*)d_in[1];
  const float* prenet_w1 = (const float*)d_in[2];
  const float* prenet_w2 = (const float*)d_in[3];
  const float* w_ih      = (const float*)d_in[4];
  const float* w_hh      = (const float*)d_in[5];
  const float* b_ih      = (const float*)d_in[6];
  const float* b_hh      = (const float*)d_in[7];
  const float* out_w1    = (const float*)d_in[8];
  const float* out_b1    = (const float*)d_in[9];
  const float* out_w2    = (const float*)d_in[10];
  const float* out_b2    = (const float*)d_in[11];
  const int* inputs_len  = (const int*)d_in[12];
  const int* mel_lens    = (const int*)d_in[13];

  float* ws = (float*)d_ws;
  unsigned short* gatesb = (unsigned short*)ws;              // 4194304 sh (2097152 fl)
  float* zi      = ws + 2097152;              // 262144
  float* hv      = ws + 2359296;              // 1048576
  float* elp     = ws + 3407872;              // 524288 (T*B*64 float4)
  double* hm     = (double*)(ws + 3932160);   // 16384 fl = 8192 dbl ring
  unsigned short* w2frag  = (unsigned short*)(ws + 3948544); // 98304 sh
  unsigned short* h_allb  = (unsigned short*)(ws + 3997696); // 1048576 sh
  unsigned short* p2b     = (unsigned short*)(ws + 4521984); // 524288 sh
  unsigned short* p1b     = (unsigned short*)(ws + 4784128); // 524288 sh
  unsigned short* arb     = (unsigned short*)(ws + 5046272); // 262144 sh
  unsigned short* w1b     = (unsigned short*)(ws + 5177344); // 32768 sh
  unsigned short* w2b     = (unsigned short*)(ws + 5193728); // 65536 sh
  unsigned short* w_ihb   = (unsigned short*)(ws + 5226496); // 524288 sh
  unsigned short* w1hb    = (unsigned short*)(ws + 5488640); // 262144 sh
  unsigned short* w1eb    = (unsigned short*)(ws + 5619712); // 262144 sh
  unsigned short* inputsb = (unsigned short*)(ws + 5750784); // 262144 sh
  unsigned* whh16         = (unsigned*)(ws + 5881856);       // 524288 u32

  // fused prep (weights, fragments, mailbox clear) + ar fill
  conv_all<<<8000, 256, 0, stream>>>(w_ih, out_w1, inputs, prenet_w2, prenet_w1,
                                     out_w2, w_hh, w_ihb, w1hb, w1eb, inputsb,
                                     w2b, w1b, w2frag, whh16, (float*)hm);
  arb_fill<<<1024, 256, 0, stream>>>(mels, arb);

  // prenet (MFMA, bf16 out):  p1 = relu(arb @ w1b^T)  M=2048 N=256 K=128
  gemm_mfma<<<dim3(4, 32), 256, 0, stream>>>(arb, 128, w1b, 128,
                                             nullptr, nullptr, p1b, PP, 128, 1, 1);
  // p2 = relu(p1b @ w2b^T)   K=256
  gemm_mfma<<<dim3(4, 32), 256, 0, stream>>>(p1b, 256, w2b, 256,
                                             nullptr, nullptr, p2b, PP, 256, 1, 1);
  // gatesb = p2b @ w_ihb^T + b_ih + b_hh  (bf16 out)  M=2048 N=2048 K=256
  gemm_mfma<<<dim3(32, 32), 256, 0, stream>>>(p2b, 256, w_ihb, 256,
                                              b_ih, b_hh, gatesb, 2048, 256, 0, 1);
  // zi = inputsb @ w1eb^T + b1  (fp32 out)  M=512 N=512 K=512
  gemm_mfma<<<dim3(8, 8), 256, 0, stream>>>(inputsb, 512, w1eb, 512,
                                            out_b1, nullptr, zi, 512, 512, 0, 0);

  // sequential LSTM (per-batch groups, two-phase acquire, fdot2 matvec)
  lstm_seq<<<128, 256, 0, stream>>>(whh16, gatesb, h_allb, hm);

  // hv = h_allb @ w1hb^T  (fp32 out)  M=2048 N=512 K=512
  gemm_mfma<<<dim3(8, 32), 256, 0, stream>>>(h_allb, 512, w1hb, 512,
                                             nullptr, nullptr, hv, 512, 512, 0, 0);

  // fused output net + emission (MFMA) -> elp
  outnet<<<2048, 256, 0, stream>>>(hv, zi, w2frag, out_b2, mels, inputs_len, elp);

  // sequential HMM scan
  hmm_scan<<<1, 512, 0, stream>>>(elp, inputs_len, mel_lens, (float*)d_out);
}

// Round 9
// 712.627 us; speedup vs baseline: 2.5308x; 1.1204x over previous
//
#include <hip/hip_runtime.h>
#include <math.h>

// Problem constants
#define T_STEPS 256
#define BB 8
#define NSTATE 64
#define DD 80
#define PP 256
#define HH 512
#define OO 512
#define NPARAM 161   // 2*D+1
#define PLS 171      // padded row stride for params in LDS (bank spread)
#define NEG_INF_F (-1000000.0f)

#define GSTR 88      // gemm_mfma LDS row stride in ushorts

typedef __attribute__((ext_vector_type(8))) short s16x8;
typedef __attribute__((ext_vector_type(4))) float f32x4;
typedef _Float16 h2t __attribute__((ext_vector_type(2)));

union PairU { double d; float f[2]; unsigned u[2]; };

__device__ __forceinline__ float sigmoidf_(float x) { return 1.0f / (1.0f + __expf(-x)); }
__device__ __forceinline__ unsigned short bf16rne(float x) {
  union { float f; unsigned u; } v; v.f = x;
  unsigned r = (v.u + 0x7FFFu + ((v.u >> 16) & 1u)) >> 16;
  return (unsigned short)r;
}
__device__ __forceinline__ float bf2f(unsigned s) {
  union { unsigned u; float f; } v; v.u = s << 16; return v.f;
}
__device__ __forceinline__ float fdot2_(unsigned a, unsigned b, float c) {
  union { unsigned u; h2t h; } ua, ub; ua.u = a; ub.u = b;
  return __builtin_amdgcn_fdot2(ua.h, ub.h, c, false);
}
__device__ __forceinline__ unsigned packf16(float a, float b) {
  union { unsigned u; _Float16 f[2]; } p;
  p.f[0] = (_Float16)a; p.f[1] = (_Float16)b;
  return p.u;
}

// ---------------------------------------------------------------------------
// fused conversion/prep kernel: all weight reformatting + mailbox clear + arb.
// Segments over a grand linear index (items):
//  s0 w_ihb   [0,524288)          bf16 linear of w_ih [2048][256]
//  s1 w1hb    [524288,786432)     bf16 of out_w1[:, 0:512]
//  s2 w1eb    [786432,1048576)    bf16 of out_w1[:, 512:1024]
//  s3 inputsb [1048576,1310720)   bf16 linear of inputs
//  s4 w2b     [1310720,1376256)   bf16 linear of prenet_w2 [256][256]
//  s5 w1b     [1376256,1409024)   bf16 [256][128] zero-padded K of prenet_w1
//  s6 w2frag  [1409024,1507328)   MFMA B-fragments of out_w2 (verified layout)
//  s7 whh16   [1507328,2031616)   fp16-pair pack of w_hh rows (uint writes)
//  s8 hm      [2031616,2048000)   mailbox ring clear (float writes)
//  s9 arb     [2048000,2310144)   bf16 zero-K-padded AR input [2048][128]
// ---------------------------------------------------------------------------
__global__ __launch_bounds__(256)
void conv_all(const float* __restrict__ w_ih, const float* __restrict__ out_w1,
              const float* __restrict__ inputs, const float* __restrict__ pw2,
              const float* __restrict__ pw1, const float* __restrict__ w2,
              const float* __restrict__ w_hh, const float* __restrict__ mels,
              unsigned short* __restrict__ w_ihb, unsigned short* __restrict__ w1hb,
              unsigned short* __restrict__ w1eb, unsigned short* __restrict__ inputsb,
              unsigned short* __restrict__ w2b, unsigned short* __restrict__ w1b,
              unsigned short* __restrict__ w2frag, unsigned* __restrict__ whh16,
              float* __restrict__ hmf, unsigned short* __restrict__ arb)
{
  int idx = blockIdx.x * 256 + threadIdx.x;
  if (idx < 524288) {
    w_ihb[idx] = bf16rne(w_ih[idx]);
  } else if (idx < 786432) {
    int i = idx - 524288; int r = i >> 9, c = i & 511;
    w1hb[i] = bf16rne(out_w1[(size_t)r * 1024 + c]);
  } else if (idx < 1048576) {
    int i = idx - 786432; int r = i >> 9, c = i & 511;
    w1eb[i] = bf16rne(out_w1[(size_t)r * 1024 + 512 + c]);
  } else if (idx < 1310720) {
    int i = idx - 1048576;
    inputsb[i] = bf16rne(inputs[i]);
  } else if (idx < 1376256) {
    int i = idx - 1310720;
    w2b[i] = bf16rne(pw2[i]);
  } else if (idx < 1409024) {
    int i = idx - 1376256; int r = i >> 7, c = i & 127;
    w1b[i] = (c < DD) ? bf16rne(pw1[r * DD + c]) : (unsigned short)0;
  } else if (idx < 1507328) {
    int i = idx - 1409024;
    int j = i & 7, lane = (i >> 3) & 63, nt = (i >> 9) % 12, kb = i / 6144;
    int p = nt * 16 + (lane & 15);
    int o = kb * 32 + ((lane >> 4) << 3) + j;
    float v = (p < NPARAM) ? w2[p * OO + o] : 0.0f;
    w2frag[i] = bf16rne(v);
  } else if (idx < 2031616) {
    int i = idx - 1507328;                 // uint index: row*256 + pair
    int gr = i >> 8, pp = i & 255;
    const float* src = &w_hh[(size_t)gr * HH + pp * 2];
    whh16[i] = packf16(src[0], src[1]);
  } else if (idx < 2048000) {
    hmf[idx - 2031616] = 0.0f;             // mailbox ring
  } else if (idx < 2310144) {
    int i = idx - 2048000;
    int c = i & 127; int r = i >> 7; int b = r & 7; int t = r >> 3;
    float v = (t == 0 || c >= DD) ? 0.0f : mels[(b * DD + c) * T_STEPS + (t - 1)];
    arb[i] = bf16rne(v);
  }
}

// ---------------------------------------------------------------------------
// bf16 MFMA GEMM (fragment conventions verified by outnet).
// obf=1: emit bf16 (ushort) C; else fp32.
// ---------------------------------------------------------------------------
__global__ __launch_bounds__(256)
void gemm_mfma(const unsigned short* __restrict__ A, int lda,
               const unsigned short* __restrict__ B, int ldb,
               const float* __restrict__ bias1, const float* __restrict__ bias2,
               void* __restrict__ Cout, int N, int K, int relu, int obf)
{
  __shared__ unsigned short As[64 * GSTR];
  __shared__ unsigned short Bs[64 * GSTR];
  const int tid = threadIdx.x;
  const int lane = tid & 63, wv = tid >> 6;
  const int m0 = blockIdx.y * 64, n0 = blockIdx.x * 64;
  const int srow = tid >> 3, scol = (tid & 7) * 8;

  f32x4 acc[4];
#pragma unroll
  for (int m = 0; m < 4; ++m) acc[m] = (f32x4){0.f, 0.f, 0.f, 0.f};

  for (int k0 = 0; k0 < K; k0 += 64) {
    __syncthreads();
    *(float4*)&As[srow * GSTR + scol] =
        *(const float4*)&A[(size_t)(m0 + srow) * lda + k0 + scol];
    *(float4*)&As[(srow + 32) * GSTR + scol] =
        *(const float4*)&A[(size_t)(m0 + srow + 32) * lda + k0 + scol];
    *(float4*)&Bs[srow * GSTR + scol] =
        *(const float4*)&B[(size_t)(n0 + srow) * ldb + k0 + scol];
    *(float4*)&Bs[(srow + 32) * GSTR + scol] =
        *(const float4*)&B[(size_t)(n0 + srow + 32) * ldb + k0 + scol];
    __syncthreads();
#pragma unroll
    for (int ks = 0; ks < 2; ++ks) {
      const int kk = ks * 32 + 8 * (lane >> 4);
      s16x8 bfr = *(const s16x8*)&Bs[(wv * 16 + (lane & 15)) * GSTR + kk];
#pragma unroll
      for (int m = 0; m < 4; ++m) {
        s16x8 afr = *(const s16x8*)&As[(m * 16 + (lane & 15)) * GSTR + kk];
        acc[m] = __builtin_amdgcn_mfma_f32_16x16x32_bf16(afr, bfr, acc[m], 0, 0, 0);
      }
    }
  }
  const int cn = n0 + wv * 16 + (lane & 15);
  float bj = 0.f;
  if (bias1) bj += bias1[cn];
  if (bias2) bj += bias2[cn];
  const int rbase = m0 + (lane >> 4) * 4;
#pragma unroll
  for (int m = 0; m < 4; ++m)
#pragma unroll
    for (int r = 0; r < 4; ++r) {
      float v = acc[m][r] + bj;
      if (relu) v = fmaxf(v, 0.f);
      size_t ci = (size_t)(rbase + m * 16 + r) * N + cn;
      if (obf) ((unsigned short*)Cout)[ci] = bf16rne(v);
      else     ((float*)Cout)[ci] = v;
    }
}

// ---------------------------------------------------------------------------
// persistent sequential LSTM v9: R7's verified agent-scope tagged mailbox
// (NO XCD fast path — R8's L2 scheme deadlocked: cannot bootstrap coherent
// agreement over a non-coherent channel), with 512 threads and 2 barriers
// per step: matvec k-split 4-way; gate reduction folded into the update wave.
// Mailbox: per batch, 256 words {2xfp16 h, 32b tag}, ring depth 4, cleared
// by conv_all each launch. Each thread (tid<256) spins on exactly ONE word.
// ---------------------------------------------------------------------------
__global__ __launch_bounds__(512)
void lstm_seq(const unsigned* __restrict__ whh16, const unsigned short* __restrict__ gatesb,
              unsigned short* __restrict__ h_allb, double* __restrict__ hm)
{
  __shared__ unsigned hl16[256];   // h[t-1] as 256 fp16-pairs
  __shared__ float red[4][128];    // k-quarter partial sums per row
  const int tid = threadIdx.x;
  const int b = blockIdx.x & 7;       // batch group
  const int s = blockIdx.x >> 3;      // j-slice 0..15 (32 units)
  const int j0 = s * 32;
  const int row = tid & 127;          // g*32+jl
  const int kq  = tid >> 7;           // k-quarter 0..3
  const int g = row >> 5, jl = row & 31;
  const int gr = g * HH + j0 + jl;    // global gate-row

  // weights -> VGPRs: 64 fp16-pairs = 128 k elems (this thread's k-quarter)
  unsigned wreg[64];
  {
    const unsigned* wp = &whh16[(size_t)gr * 256 + kq * 64];
#pragma unroll
    for (int c = 0; c < 64; ++c) wreg[c] = wp[c];
  }
  float c_reg = 0.f;

  for (int t = 0; t < T_STEPS; ++t) {
    // prefetch this thread's 4 gate-x values (tid<32; independent of poll)
    float gxv[4] = {0.f, 0.f, 0.f, 0.f};
    if (tid < 32) {
      const unsigned short* gp = &gatesb[((size_t)t * BB + b) * 2048 + j0 + tid];
#pragma unroll
      for (int gg = 0; gg < 4; ++gg) gxv[gg] = bf2f(gp[gg * HH]);
    }

    // ---- acquire h[t-1]: tid<256 spins on its own tagged word ----
    if (t == 0) {
      if (tid < 256) hl16[tid] = 0u;
    } else if (tid < 256) {
      const double* ring = hm + ((size_t)((t - 1) & 3) * BB + b) * 256;
      PairU w;
      for (;;) {
        w.d = __hip_atomic_load(&ring[tid], __ATOMIC_RELAXED, __HIP_MEMORY_SCOPE_AGENT);
        if (w.u[1] == (unsigned)t) break;
        __builtin_amdgcn_s_sleep(1);
      }
      hl16[tid] = w.u[0];
    }
    __syncthreads();   // barrier 1: h ready (also fences red reuse, see below)

    // ---- matvec: row x 128 k via fdot2, 4 chains of 16 ----
    float a0 = 0.f, a1 = 0.f, a2 = 0.f, a3 = 0.f;
    const unsigned* hp = &hl16[kq * 64];
#pragma unroll
    for (int c = 0; c < 64; c += 4) {
      a0 = fdot2_(wreg[c + 0], hp[c + 0], a0);
      a1 = fdot2_(wreg[c + 1], hp[c + 1], a1);
      a2 = fdot2_(wreg[c + 2], hp[c + 2], a2);
      a3 = fdot2_(wreg[c + 3], hp[c + 3], a3);
    }
    red[kq][row] = (a0 + a1) + (a2 + a3);
    __syncthreads();   // barrier 2: partials ready

    // ---- update wave: 16 red reads + gates + publish (no 3rd barrier) ----
    if (tid < 32) {
      float iv = red[0][tid]       + red[1][tid]       + red[2][tid]       + red[3][tid]       + gxv[0];
      float fv = red[0][32 + tid]  + red[1][32 + tid]  + red[2][32 + tid]  + red[3][32 + tid]  + gxv[1];
      float gv = red[0][64 + tid]  + red[1][64 + tid]  + red[2][64 + tid]  + red[3][64 + tid]  + gxv[2];
      float ov = red[0][96 + tid]  + red[1][96 + tid]  + red[2][96 + tid]  + red[3][96 + tid]  + gxv[3];
      float ct = sigmoidf_(fv) * c_reg + sigmoidf_(iv) * tanhf(gv);
      c_reg = ct;
      float h = sigmoidf_(ov) * tanhf(ct);
      float hpart = __shfl_xor(h, 1);   // partner unit jl^1
      if ((tid & 1) == 0) {
        PairU pv;
        pv.u[0] = packf16(h, hpart);
        pv.u[1] = (unsigned)(t + 1);
        __hip_atomic_store(&hm[((size_t)(t & 3) * BB + b) * 256 + s * 16 + (tid >> 1)],
                           pv.d, __ATOMIC_RELAXED, __HIP_MEMORY_SCOPE_AGENT);
      }
      h_allb[((size_t)t * BB + b) * HH + j0 + tid] = bf16rne(h);
    }
    // No trailing barrier: next iteration's hl16/red writes happen only after
    // barrier 1/2 of that iteration; every thread's reads of this iteration
    // precede its barrier-2 crossing. (Update wave's red reads precede its
    // next barrier-1 crossing, which all writers must also pass.)
  }
}

// ---------------------------------------------------------------------------
// fused output net + emission, MFMA (verified layout). Block per (t,b).
// Emissions packed into elp float4 {em, lsn, lsp, 0}.
// ---------------------------------------------------------------------------
__global__ __launch_bounds__(256)
void outnet(const float* __restrict__ hv, const float* __restrict__ zi,
            const unsigned short* __restrict__ w2frag, const float* __restrict__ b2,
            const float* __restrict__ mels, const int* __restrict__ inputs_len,
            float* __restrict__ elp)
{
  __shared__ float hvs[OO];
  __shared__ float xts[96];
  __shared__ s16x8 Afr[2][256];
  __shared__ float pl[64 * PLS];
  const int tid = threadIdx.x;
  const int tb = blockIdx.x;
  const int t = tb >> 3, b = tb & 7;
  const int lane = tid & 63, wv = tid >> 6;

  if (tid < 128) *(float4*)&hvs[tid * 4] = *(const float4*)&hv[(size_t)tb * OO + tid * 4];
  if (tid < DD) xts[tid] = mels[(b * DD + tid) * T_STEPS + t];
  __syncthreads();

  const int n_state = wv * 16 + (lane & 15);
  const int osub = (lane >> 4) * 8;
  const float* zbase = zi + (size_t)(b * 64 + n_state) * OO;

  auto genA = [&](int kb, int buf) {
    int ob = kb * 32 + osub;
    float4 z0 = *(const float4*)&zbase[ob];
    float4 z1 = *(const float4*)&zbase[ob + 4];
    float4 h0 = *(const float4*)&hvs[ob];
    float4 h1 = *(const float4*)&hvs[ob + 4];
    s16x8 s;
    s[0] = bf16rne(fmaxf(z0.x + h0.x, 0.f));
    s[1] = bf16rne(fmaxf(z0.y + h0.y, 0.f));
    s[2] = bf16rne(fmaxf(z0.z + h0.z, 0.f));
    s[3] = bf16rne(fmaxf(z0.w + h0.w, 0.f));
    s[4] = bf16rne(fmaxf(z1.x + h1.x, 0.f));
    s[5] = bf16rne(fmaxf(z1.y + h1.y, 0.f));
    s[6] = bf16rne(fmaxf(z1.z + h1.z, 0.f));
    s[7] = bf16rne(fmaxf(z1.w + h1.w, 0.f));
    Afr[buf][tid] = s;
  };
  genA(0, 0);

  f32x4 acc[4][3];
#pragma unroll
  for (int m = 0; m < 4; ++m)
#pragma unroll
    for (int n = 0; n < 3; ++n) acc[m][n] = (f32x4){0.f, 0.f, 0.f, 0.f};

  const unsigned short* bfp = w2frag + ((size_t)(wv * 3) * 64 + lane) * 8;

  for (int kb = 0; kb < 16; ++kb) {
    __syncthreads();
    s16x8 bf[3];
#pragma unroll
    for (int ntl = 0; ntl < 3; ++ntl)
      bf[ntl] = *(const s16x8*)&bfp[(size_t)kb * 6144 + ntl * 512];
    if (kb < 15) genA(kb + 1, (kb + 1) & 1);
    s16x8 af[4];
#pragma unroll
    for (int m = 0; m < 4; ++m) af[m] = Afr[kb & 1][m * 64 + lane];
#pragma unroll
    for (int m = 0; m < 4; ++m)
#pragma unroll
      for (int ntl = 0; ntl < 3; ++ntl)
        acc[m][ntl] = __builtin_amdgcn_mfma_f32_16x16x32_bf16(af[m], bf[ntl], acc[m][ntl], 0, 0, 0);
  }

  const int prow4 = (lane >> 4) * 4;
#pragma unroll
  for (int ntl = 0; ntl < 3; ++ntl) {
    int p = (wv * 3 + ntl) * 16 + (lane & 15);
    if (p < NPARAM) {
      float bb2 = b2[p];
#pragma unroll
      for (int m = 0; m < 4; ++m)
#pragma unroll
        for (int r = 0; r < 4; ++r)
          pl[(m * 16 + prow4 + r) * PLS + p] = acc[m][ntl][r] + bb2;
    }
  }
  __syncthreads();

  const int ne = tid >> 2, dq = tid & 3;
  float s = 0.f;
  for (int d = dq * 20; d < dq * 20 + 20; ++d) {
    float mean = pl[ne * PLS + d];
    float sp   = pl[ne * PLS + 80 + d];
    float x = xts[d];
    float sf = (sp > 20.f) ? sp : log1pf(__expf(sp));
    float sd = fmaxf(sf, 0.001f);
    float zz = (x - mean) / sd;
    s += -0.5f * zz * zz - __logf(sd) - 0.91893853320467274f;
  }
  s += __shfl_xor(s, 1);
  s += __shfl_xor(s, 2);
  if (dq == 0) {
    int ilen = inputs_len[b];
    float tv = pl[ne * PLS + 160];
    float4 o;
    o.x = (ne < ilen) ? s : 0.f;                       // emission (masked)
    o.y = __logf(fmaxf(sigmoidf_(-tv), 1e-4f));        // log sig(-tv)
    o.z = __logf(fmaxf(sigmoidf_(tv), 1e-4f));         // log sig(tv)
    o.w = 0.f;
    *(float4*)&elp[((size_t)tb * NSTATE + ne) * 4] = o;
  }
}

// ---------------------------------------------------------------------------
// sequential HMM forward scan: 1 block, wave per batch, float4 loads + prefetch.
// ---------------------------------------------------------------------------
__global__ __launch_bounds__(512)
void hmm_scan(const float* __restrict__ elp, const int* __restrict__ inputs_len,
              const int* __restrict__ mel_lens, float* __restrict__ out)
{
  const int tid = threadIdx.x;
  const int b = tid >> 6, n = tid & 63;
  const int ilen = inputs_len[b], mlen = mel_lens[b];
  const bool mask = n < ilen;
  const float4* e4 = (const float4*)elp;
  const size_t base = (size_t)b * NSTATE + n;
  float alpha = 0.f, slc = 0.f, la = NEG_INF_F, llsp = 0.f;
  float4 cur = e4[base];

  for (int t = 0; t < T_STEPS; ++t) {
    float4 nxt = {0.f, 0.f, 0.f, 0.f};
    if (t + 1 < T_STEPS) nxt = e4[base + (size_t)(t + 1) * BB * NSTATE];
    float e = cur.x, ln_ = cur.y, lp_ = cur.z;
    float at;
    if (t == 0) {
      at = ((n == 0) ? 0.f : NEG_INF_F) + e;
    } else {
      float stay = alpha + ln_;
      float lvs = alpha + lp_;
      float lv = __shfl_up(lvs, 1, 64);
      if (n == 0) lv = NEG_INF_F;
      float mx = fmaxf(stay, lv), mn = fminf(stay, lv);
      float tt = mask ? (mx + log1pf(__expf(mn - mx))) : NEG_INF_F;
      at = e + tt;
    }
    float m = at;
#pragma unroll
    for (int off = 1; off < 64; off <<= 1) m = fmaxf(m, __shfl_xor(m, off));
    float es = __expf(at - m);
#pragma unroll
    for (int off = 1; off < 64; off <<= 1) es += __shfl_xor(es, off);
    float logc = m + __logf(es);
    alpha = at - logc;
    if (t < mlen) slc += logc;
    if (t == mlen - 1) { la = mask ? alpha : NEG_INF_F; llsp = lp_; }
    cur = nxt;
  }

  float v = la + ((n == ilen - 1) ? llsp : NEG_INF_F);
  float m = v;
#pragma unroll
  for (int off = 1; off < 64; off <<= 1) m = fmaxf(m, __shfl_xor(m, off));
  float es = __expf(v - m);
#pragma unroll
  for (int off = 1; off < 64; off <<= 1) es += __shfl_xor(es, off);
  float sfin = m + __logf(es);
  if (n == 0) out[b] = slc + sfin;
}

// ---------------------------------------------------------------------------
extern "C" void kernel_launch(void* const* d_in, const int* in_sizes, int n_in,
                              void* d_out, int out_size, void* d_ws, size_t ws_size,
                              hipStream_t stream)
{
  const float* inputs    = (const float*)d_in[0];
  const float* mels      = (const float*)d_in[1];
  const float* prenet_w1 = (const float*)d_in[2];
  const float* prenet_w2 = (const float*)d_in[3];
  const float* w_ih      = (const float*)d_in[4];
  const float* w_hh      = (const float*)d_in[5];
  const float* b_ih      = (const float*)d_in[6];
  const float* b_hh      = (const float*)d_in[7];
  const float* out_w1    = (const float*)d_in[8];
  const float* out_b1    = (const float*)d_in[9];
  const float* out_w2    = (const float*)d_in[10];
  const float* out_b2    = (const float*)d_in[11];
  const int* inputs_len  = (const int*)d_in[12];
  const int* mel_lens    = (const int*)d_in[13];

  float* ws = (float*)d_ws;
  unsigned short* gatesb = (unsigned short*)ws;              // 4194304 sh (2097152 fl)
  float* zi      = ws + 2097152;              // 262144
  float* hv      = ws + 2359296;              // 1048576
  float* elp     = ws + 3407872;              // 524288 (T*B*64 float4)
  double* hm     = (double*)(ws + 3932160);   // 16384 fl = 8192 dbl ring
  unsigned short* w2frag  = (unsigned short*)(ws + 3948544); // 98304 sh
  unsigned short* h_allb  = (unsigned short*)(ws + 3997696); // 1048576 sh
  unsigned short* p2b     = (unsigned short*)(ws + 4521984); // 524288 sh
  unsigned short* p1b     = (unsigned short*)(ws + 4784128); // 524288 sh
  unsigned short* arb     = (unsigned short*)(ws + 5046272); // 262144 sh
  unsigned short* w1b     = (unsigned short*)(ws + 5177344); // 32768 sh
  unsigned short* w2b     = (unsigned short*)(ws + 5193728); // 65536 sh
  unsigned short* w_ihb   = (unsigned short*)(ws + 5226496); // 524288 sh
  unsigned short* w1hb    = (unsigned short*)(ws + 5488640); // 262144 sh
  unsigned short* w1eb    = (unsigned short*)(ws + 5619712); // 262144 sh
  unsigned short* inputsb = (unsigned short*)(ws + 5750784); // 262144 sh
  unsigned* whh16         = (unsigned*)(ws + 5881856);       // 524288 u32

  // fused prep (weights, fragments, mailbox clear, arb)  — 2310144 items
  conv_all<<<9024, 256, 0, stream>>>(w_ih, out_w1, inputs, prenet_w2, prenet_w1,
                                     out_w2, w_hh, mels, w_ihb, w1hb, w1eb,
                                     inputsb, w2b, w1b, w2frag, whh16,
                                     (float*)hm, arb);

  // prenet (MFMA, bf16 out):  p1 = relu(arb @ w1b^T)  M=2048 N=256 K=128
  gemm_mfma<<<dim3(4, 32), 256, 0, stream>>>(arb, 128, w1b, 128,
                                             nullptr, nullptr, p1b, PP, 128, 1, 1);
  // p2 = relu(p1b @ w2b^T)   K=256
  gemm_mfma<<<dim3(4, 32), 256, 0, stream>>>(p1b, 256, w2b, 256,
                                             nullptr, nullptr, p2b, PP, 256, 1, 1);
  // gatesb = p2b @ w_ihb^T + b_ih + b_hh  (bf16 out)  M=2048 N=2048 K=256
  gemm_mfma<<<dim3(32, 32), 256, 0, stream>>>(p2b, 256, w_ihb, 256,
                                              b_ih, b_hh, gatesb, 2048, 256, 0, 1);
  // zi = inputsb @ w1eb^T + b1  (fp32 out)  M=512 N=512 K=512
  gemm_mfma<<<dim3(8, 8), 256, 0, stream>>>(inputsb, 512, w1eb, 512,
                                            out_b1, nullptr, zi, 512, 512, 0, 0);

  // sequential LSTM (per-batch groups, agent-scope tagged mailbox, 512 thr)
  lstm_seq<<<128, 512, 0, stream>>>(whh16, gatesb, h_allb, hm);

  // hv = h_allb @ w1hb^T  (fp32 out)  M=2048 N=512 K=512
  gemm_mfma<<<dim3(8, 32), 256, 0, stream>>>(h_allb, 512, w1hb, 512,
                                             nullptr, nullptr, hv, 512, 512, 0, 0);

  // fused output net + emission (MFMA) -> elp
  outnet<<<2048, 256, 0, stream>>>(hv, zi, w2frag, out_b2, mels, inputs_len, elp);

  // sequential HMM scan
  hmm_scan<<<1, 512, 0, stream>>>(elp, inputs_len, mel_lens, (float*)d_out);
}